// Round 2
// baseline (1045.961 us; speedup 1.0000x reference)
//
#include <hip/hip_runtime.h>
#include <math.h>

#define B_ 2
#define N_ 1000
#define F_ 8
#define T_ 12
#define H_ 64
#define G_ 24      // B*T
#define NF_ 8000   // N*F
#define ER_ 2000
#define EC_ 24000

__device__ __forceinline__ float sigf(float x){ return 1.0f/(1.0f+__expf(-x)); }

// broadcast lane k's value of v to all lanes (VALU readlane, no LDS traffic)
__device__ __forceinline__ float rl(float v, int k){
    return __int_as_float(__builtin_amdgcn_readlane(__float_as_int(v), k));
}

// ---------------------------------------------------------------- ws = mean over F
__global__ __launch_bounds__(64) void k_ws(const float* __restrict__ x, float* __restrict__ ws){
    int idx = blockIdx.x;            // g*N + n
    int h = threadIdx.x;
    int g = idx / N_, n = idx % N_;
    int b = g / T_, t = g % T_;
    const float* base = x + ((size_t)(b*N_+n)*F_*T_ + t)*H_ + h;
    float s = 0.f;
    #pragma unroll
    for (int f=0; f<F_; ++f) s += base[(size_t)f*T_*H_];
    ws[(size_t)idx*H_ + h] = s * (1.0f/F_);
}

// ---------------------------------------------------------------- y = xin @ W(64x64) + b
// FN=true: rows gathered from x as fn[g, j=n*F+f, :]
template<int R, bool FN>
__global__ __launch_bounds__(64) void k_mm64(const float* __restrict__ xin,
                                             const float* __restrict__ x,
                                             const float* __restrict__ W,
                                             const float* __restrict__ bias,
                                             float* __restrict__ y){
    int h = threadIdx.x;
    int r0 = blockIdx.x * R;
    float row[R];
    #pragma unroll
    for (int r=0;r<R;++r){
        int rr = r0 + r;
        if (FN){
            int g = rr / NF_, j = rr % NF_;
            int b = g / T_, t = g % T_, n = j / F_, f = j % F_;
            row[r] = x[((size_t)((b*N_+n)*F_+f)*T_ + t)*H_ + h];
        } else {
            row[r] = xin[(size_t)rr*64 + h];
        }
    }
    float acc[R];
    float bv = bias[h];
    #pragma unroll
    for (int r=0;r<R;++r) acc[r]=bv;
    #pragma unroll 4
    for (int k=0;k<64;++k){
        float w = W[k*64+h];
        #pragma unroll
        for (int r=0;r<R;++r) acc[r] += rl(row[r],k)*w;
    }
    #pragma unroll
    for (int r=0;r<R;++r) y[(size_t)(r0+r)*64 + h] = acc[r];
}

// ---------------------------------------------------------------- scatter-add messages
// 256 threads = 4 edges; idx = g*E + e
__global__ __launch_bounds__(256) void k_scatter(const float* __restrict__ y,
                                                 const int* __restrict__ src,
                                                 const int* __restrict__ dst,
                                                 const float* __restrict__ ew,
                                                 const float* __restrict__ lw,
                                                 const float* __restrict__ gate,
                                                 float* __restrict__ aggr,
                                                 int E, int nseg){
    int h = threadIdx.x & 63;
    int idx = blockIdx.x*4 + (threadIdx.x >> 6);
    int g = idx / E, e = idx % E;
    float gs = sigf(gate[0]);
    float mw = gs*ew[e] + (1.f-gs)*sigf(lw[e]);
    int s = src[e], d = dst[e];
    float v = mw * y[((size_t)g*nseg + s)*64 + h];
    atomicAdd(&aggr[((size_t)g*nseg + d)*64 + h], v);
}

// ---------------------------------------------------------------- u = relu(concat[aggr,x] @ Wu(128x64) + b)
template<int R, bool FN>
__global__ __launch_bounds__(64) void k_update(const float* __restrict__ aggr,
                                               const float* __restrict__ xin,
                                               const float* __restrict__ x,
                                               const float* __restrict__ Wu,
                                               const float* __restrict__ bu,
                                               float* __restrict__ u){
    int h = threadIdx.x;
    int r0 = blockIdx.x * R;
    float ra[R], rx[R];
    #pragma unroll
    for (int r=0;r<R;++r){
        int rr = r0 + r;
        ra[r] = aggr[(size_t)rr*64 + h];
        if (FN){
            int g = rr / NF_, j = rr % NF_;
            int b = g / T_, t = g % T_, n = j / F_, f = j % F_;
            rx[r] = x[((size_t)((b*N_+n)*F_+f)*T_ + t)*H_ + h];
        } else {
            rx[r] = xin[(size_t)rr*64 + h];
        }
    }
    float acc[R];
    float bv = bu[h];
    #pragma unroll
    for (int r=0;r<R;++r) acc[r]=bv;
    #pragma unroll 4
    for (int k=0;k<64;++k){
        float w = Wu[k*64+h];
        #pragma unroll
        for (int r=0;r<R;++r) acc[r] += rl(ra[r],k)*w;
    }
    #pragma unroll 4
    for (int k=0;k<64;++k){
        float w = Wu[(64+k)*64+h];
        #pragma unroll
        for (int r=0;r<R;++r) acc[r] += rl(rx[r],k)*w;
    }
    #pragma unroll
    for (int r=0;r<R;++r) u[(size_t)(r0+r)*64 + h] = fmaxf(acc[r], 0.f);
}

// ---------------------------------------------------------------- fusion MLP
template<int R>
__global__ __launch_bounds__(64) void k_fusion(const float* __restrict__ fnu,
                                               const float* __restrict__ wsu,
                                               const float* __restrict__ W1,
                                               const float* __restrict__ b1,
                                               const float* __restrict__ W2,
                                               const float* __restrict__ b2,
                                               float* __restrict__ fused){
    int h = threadIdx.x;
    int r0 = blockIdx.x * R;
    float rf[R], rw[R];
    #pragma unroll
    for (int r=0;r<R;++r){
        int rr = r0 + r;           // g*NF + j
        int g = rr / NF_, j = rr % NF_;
        int n = j / F_;
        rf[r] = fnu[(size_t)rr*64 + h];
        rw[r] = wsu[((size_t)g*N_ + n)*64 + h];
    }
    float acc[R];
    float bv = b1[h];
    #pragma unroll
    for (int r=0;r<R;++r) acc[r]=bv;
    #pragma unroll 4
    for (int k=0;k<64;++k){
        float w = W1[k*64+h];
        #pragma unroll
        for (int r=0;r<R;++r) acc[r] += rl(rf[r],k)*w;
    }
    #pragma unroll 4
    for (int k=0;k<64;++k){
        float w = W1[(64+k)*64+h];
        #pragma unroll
        for (int r=0;r<R;++r) acc[r] += rl(rw[r],k)*w;
    }
    float hreg[R];
    #pragma unroll
    for (int r=0;r<R;++r) hreg[r] = fmaxf(acc[r], 0.f);
    float acc2[R];
    float bv2 = b2[h];
    #pragma unroll
    for (int r=0;r<R;++r) acc2[r]=bv2;
    #pragma unroll 4
    for (int k=0;k<64;++k){
        float w = W2[k*64+h];
        #pragma unroll
        for (int r=0;r<R;++r) acc2[r] += rl(hreg[r],k)*w;
    }
    #pragma unroll
    for (int r=0;r<R;++r) fused[(size_t)(r0+r)*64 + h] = acc2[r];
}

// ---------------------------------------------------------------- per-row temporal transformer
#define BSTR 196   // LDS row stride for qkv (floats): kills qt-stride bank conflicts, keeps 16B align
#define OSTR 65

__device__ __forceinline__ void ln64(const float* in, float* o, float g, float bb){
    #pragma unroll
    for (int t=0;t<T_;++t){
        float v = in[t];
        float s = v;
        #pragma unroll
        for (int off=32; off>0; off>>=1) s += __shfl_xor(s, off, 64);
        float mean = s * (1.0f/64.0f);
        float d = v - mean;
        float q = d*d;
        #pragma unroll
        for (int off=32; off>0; off>>=1) q += __shfl_xor(q, off, 64);
        o[t] = d * rsqrtf(q*(1.0f/64.0f) + 1e-5f) * g + bb;
    }
}

__global__ __launch_bounds__(64,3) void k_transformer(
    const float* __restrict__ fused,
    const float* __restrict__ ln1g, const float* __restrict__ ln1b,
    const float* __restrict__ ln2g, const float* __restrict__ ln2b,
    const float* __restrict__ Wqkv, const float* __restrict__ bqkv,
    const float* __restrict__ Wo,   const float* __restrict__ bo,
    const float* __restrict__ W1,   const float* __restrict__ b1,
    const float* __restrict__ W2,   const float* __restrict__ b2,
    float* __restrict__ out)
{
    __shared__ float buf[T_*BSTR];    // qkv per t: [q 0..63 | k 64..127 | v 128..191]
    __shared__ float obuf[T_*OSTR];   // attention output
    int h = threadIdx.x;
    int r = blockIdx.x;               // (b*N+n)*F + f
    int b = r / (N_*F_);
    int rem = r % (N_*F_);
    int n = rem / F_, f = rem % F_;

    float sreg[T_], xreg[T_];
    #pragma unroll
    for (int t=0;t<T_;++t)
        sreg[t] = fused[((size_t)(b*T_+t)*NF_ + n*F_ + f)*64 + h];

    // LN1 -> xreg
    ln64(sreg, xreg, ln1g[h], ln1b[h]);

    // QKV: 3 output columns per thread
    {
        float a0[T_], a1[T_], a2[T_];
        float b0 = bqkv[h], b1v = bqkv[64+h], b2v = bqkv[128+h];
        #pragma unroll
        for (int t=0;t<T_;++t){ a0[t]=b0; a1[t]=b1v; a2[t]=b2v; }
        #pragma unroll 4
        for (int k=0;k<64;++k){
            float w0 = Wqkv[k*192 + h];
            float w1 = Wqkv[k*192 + 64 + h];
            float w2 = Wqkv[k*192 + 128 + h];
            #pragma unroll
            for (int t=0;t<T_;++t){
                float bb = rl(xreg[t], k);
                a0[t] += bb*w0; a1[t] += bb*w1; a2[t] += bb*w2;
            }
        }
        #pragma unroll
        for (int t=0;t<T_;++t){
            buf[t*BSTR + h]       = a0[t];
            buf[t*BSTR + 64 + h]  = a1[t];
            buf[t*BSTR + 128 + h] = a2[t];
        }
    }
    __syncthreads();

    // attention (48 lanes: head = h/12, qt = h%12)
    if (h < 48){
        int head = h / 12, qt = h % 12;
        const float4* qv = (const float4*)&buf[qt*BSTR + head*16];
        float sc[T_];
        float mx = -1e30f;
        #pragma unroll
        for (int kt=0;kt<T_;++kt){
            const float4* kv = (const float4*)&buf[kt*BSTR + 64 + head*16];
            float a = 0.f;
            #pragma unroll
            for (int d4=0; d4<4; ++d4){
                float4 qq = qv[d4], kk = kv[d4];
                a += qq.x*kk.x + qq.y*kk.y + qq.z*kk.z + qq.w*kk.w;
            }
            a *= 0.25f;
            sc[kt] = a;
            mx = fmaxf(mx, a);
        }
        float den = 0.f;
        #pragma unroll
        for (int kt=0;kt<T_;++kt){ sc[kt] = __expf(sc[kt]-mx); den += sc[kt]; }
        float inv = 1.0f/den;
        #pragma unroll
        for (int d=0; d<16; ++d){
            float acc = 0.f;
            #pragma unroll
            for (int kt=0;kt<T_;++kt) acc += sc[kt]*buf[kt*BSTR + 128 + head*16 + d];
            obuf[qt*OSTR + head*16 + d] = acc*inv;
        }
    }
    __syncthreads();
    #pragma unroll
    for (int t=0;t<T_;++t) xreg[t] = obuf[t*OSTR + h];

    // proj + residual -> sreg
    {
        float acc[T_];
        float bv = bo[h];
        #pragma unroll
        for (int t=0;t<T_;++t) acc[t]=bv;
        #pragma unroll 4
        for (int k=0;k<64;++k){
            float w = Wo[k*64+h];
            #pragma unroll
            for (int t=0;t<T_;++t) acc[t] += rl(xreg[t],k)*w;
        }
        #pragma unroll
        for (int t=0;t<T_;++t) sreg[t] += acc[t];
    }

    // LN2 -> xreg
    ln64(sreg, xreg, ln2g[h], ln2b[h]);

    // FFN1 + exact gelu: 4 output columns per thread -> hid[c][t]
    float hid[4][T_];
    {
        #pragma unroll
        for (int c=0;c<4;++c){
            float bv = b1[c*64+h];
            #pragma unroll
            for (int t=0;t<T_;++t) hid[c][t]=bv;
        }
        #pragma unroll 2
        for (int k=0;k<64;++k){
            float w0 = W1[k*256 + h];
            float w1 = W1[k*256 + 64 + h];
            float w2 = W1[k*256 + 128 + h];
            float w3 = W1[k*256 + 192 + h];
            #pragma unroll
            for (int t=0;t<T_;++t){
                float bb = rl(xreg[t], k);
                hid[0][t] += bb*w0; hid[1][t] += bb*w1;
                hid[2][t] += bb*w2; hid[3][t] += bb*w3;
            }
        }
        #pragma unroll
        for (int c=0;c<4;++c)
            #pragma unroll
            for (int t=0;t<T_;++t){
                float a = hid[c][t];
                hid[c][t] = 0.5f*a*(1.0f + erff(a*0.70710678118654752f));
            }
    }

    // FFN2 + residual + mean over T
    {
        float acc[T_];
        float bv = b2[h];
        #pragma unroll
        for (int t=0;t<T_;++t) acc[t]=bv;
        #pragma unroll
        for (int c=0;c<4;++c){
            #pragma unroll 4
            for (int k=0;k<64;++k){
                float w = W2[(c*64+k)*64+h];
                #pragma unroll
                for (int t=0;t<T_;++t) acc[t] += rl(hid[c][t],k)*w;
            }
        }
        float m = 0.f;
        #pragma unroll
        for (int t=0;t<T_;++t) m += sreg[t] + acc[t];
        out[(size_t)r*64 + h] = m * (1.0f/T_);
    }
}

// ----------------------------------------------------------------
extern "C" void kernel_launch(void* const* d_in, const int* in_sizes, int n_in,
                              void* d_out, int out_size, void* d_ws, size_t ws_size,
                              hipStream_t stream) {
    const float* x      = (const float*)d_in[0];
    const int*   r_ei   = (const int*)  d_in[1];
    const float* r_ea   = (const float*)d_in[2];
    const int*   c_ei   = (const int*)  d_in[3];
    const float* c_ew   = (const float*)d_in[4];
    const float* rvWlin = (const float*)d_in[5];
    const float* rvblin = (const float*)d_in[6];
    const float* rvWupd = (const float*)d_in[7];
    const float* rvbupd = (const float*)d_in[8];
    const float* rvgate = (const float*)d_in[9];
    const float* rvlw   = (const float*)d_in[10];
    const float* csWlin = (const float*)d_in[11];
    const float* csblin = (const float*)d_in[12];
    const float* csWupd = (const float*)d_in[13];
    const float* csbupd = (const float*)d_in[14];
    const float* csgate = (const float*)d_in[15];
    const float* cslw   = (const float*)d_in[16];
    const float* fuW1   = (const float*)d_in[17];
    const float* fub1   = (const float*)d_in[18];
    const float* fuW2   = (const float*)d_in[19];
    const float* fub2   = (const float*)d_in[20];
    const float* ln1g   = (const float*)d_in[21];
    const float* ln1b   = (const float*)d_in[22];
    const float* ln2g   = (const float*)d_in[23];
    const float* ln2b   = (const float*)d_in[24];
    const float* Wqkv   = (const float*)d_in[25];
    const float* bqkv   = (const float*)d_in[26];
    const float* Wo     = (const float*)d_in[27];
    const float* bo     = (const float*)d_in[28];
    const float* ffW1   = (const float*)d_in[29];
    const float* ffb1   = (const float*)d_in[30];
    const float* ffW2   = (const float*)d_in[31];
    const float* ffb2   = (const float*)d_in[32];

    float* wsp  = (float*)d_ws;
    float* FNY  = wsp;                               // 12,288,000  (later reused as FNU)
    float* FNA  = wsp + 12288000;                    // 12,288,000  (later reused as FUSED)
    float* WS   = wsp + 24576000;                    //  1,536,000
    float* WSY  = wsp + 26112000;                    //  1,536,000
    float* WSA  = wsp + 27648000;                    //  1,536,000
    float* WSU  = wsp + 29184000;                    //  1,536,000
    float* outp = (float*)d_out;

    hipMemsetAsync(FNA, 0, (size_t)12288000*sizeof(float), stream);
    hipMemsetAsync(WSA, 0, (size_t)1536000*sizeof(float), stream);

    // watershed repr
    k_ws<<<G_*N_, 64, 0, stream>>>(x, WS);
    // node linear transforms
    k_mm64<8,false><<<(G_*N_)/8, 64, 0, stream>>>(WS, nullptr, rvWlin, rvblin, WSY);
    k_mm64<8,true ><<<(G_*NF_)/8, 64, 0, stream>>>(nullptr, x, csWlin, csblin, FNY);
    // gated scatter-add
    k_scatter<<<(G_*ER_)/4, 256, 0, stream>>>(WSY, r_ei, r_ei+ER_, r_ea, rvlw, rvgate, WSA, ER_, N_);
    k_scatter<<<(G_*EC_)/4, 256, 0, stream>>>(FNY, c_ei, c_ei+EC_, c_ew, cslw, csgate, FNA, EC_, NF_);
    // update MLPs
    k_update<8,false><<<(G_*N_)/8, 64, 0, stream>>>(WSA, WS, nullptr, rvWupd, rvbupd, WSU);
    k_update<8,true ><<<(G_*NF_)/8, 64, 0, stream>>>(FNA, nullptr, x, csWupd, csbupd, FNY); // FNU = FNY
    // fusion (writes into FNA region = FUSED)
    k_fusion<8><<<(G_*NF_)/8, 64, 0, stream>>>(FNY, WSU, fuW1, fub1, fuW2, fub2, FNA);
    // temporal transformer + time-mean -> out
    k_transformer<<<B_*N_*F_, 64, 0, stream>>>(FNA, ln1g, ln1b, ln2g, ln2b,
                                               Wqkv, bqkv, Wo, bo, ffW1, ffb1, ffW2, ffb2,
                                               outp);
}

// Round 3
// 679.655 us; speedup vs baseline: 1.5390x; 1.5390x over previous
//
#include <hip/hip_runtime.h>
#include <math.h>

#define B_ 2
#define N_ 1000
#define F_ 8
#define T_ 12
#define H_ 64
#define G_ 24      // B*T
#define NF_ 8000   // N*F
#define ER_ 2000
#define EC_ 24000

typedef short bf16x8 __attribute__((ext_vector_type(8)));
typedef float f32x4 __attribute__((ext_vector_type(4)));

#define LGKM0 do { asm volatile("s_waitcnt lgkmcnt(0)" ::: "memory"); __builtin_amdgcn_sched_barrier(0); } while(0)

__device__ __forceinline__ float sigf(float x){ return 1.0f/(1.0f+__expf(-x)); }

// f32 -> bf16 (RNE)
__device__ __forceinline__ unsigned short f2b(float f){
    unsigned u = __float_as_uint(f);
    unsigned r = (u + 0x7FFFu + ((u >> 16) & 1u)) >> 16;
    return (unsigned short)r;
}

// ---------------------------------------------------------------- ws = mean over F
__global__ __launch_bounds__(64) void k_ws(const float* __restrict__ x, float* __restrict__ ws){
    int idx = blockIdx.x;            // g*N + n
    int h = threadIdx.x;
    int g = idx / N_, n = idx % N_;
    int b = g / T_, t = g % T_;
    const float* base = x + ((size_t)(b*N_+n)*F_*T_ + t)*H_ + h;
    float s = 0.f;
    #pragma unroll
    for (int f=0; f<F_; ++f) s += base[(size_t)f*T_*H_];
    ws[(size_t)idx*H_ + h] = s * (1.0f/F_);
}

// ---------------------------------------------------------------- y = xin @ W(64x64) + b   (LDS broadcast version)
template<int R, bool FN>
__global__ __launch_bounds__(64) void k_mm64(const float* __restrict__ xin,
                                             const float* __restrict__ x,
                                             const float* __restrict__ W,
                                             const float* __restrict__ bias,
                                             float* __restrict__ y){
    __shared__ float row[R][64];
    int h = threadIdx.x;
    int r0 = blockIdx.x * R;
    for (int r=0;r<R;++r){
        int rr = r0 + r;
        if (FN){
            int g = rr / NF_, j = rr % NF_;
            int b = g / T_, t = g % T_, n = j / F_, f = j % F_;
            row[r][h] = x[((size_t)((b*N_+n)*F_+f)*T_ + t)*H_ + h];
        } else {
            row[r][h] = xin[(size_t)rr*64 + h];
        }
    }
    __syncthreads();
    float acc[R];
    float bv = bias[h];
    #pragma unroll
    for (int r=0;r<R;++r) acc[r]=bv;
    for (int k=0;k<64;++k){
        float w = W[k*64+h];
        #pragma unroll
        for (int r=0;r<R;++r) acc[r] += row[r][k]*w;
    }
    for (int r=0;r<R;++r) y[(size_t)(r0+r)*64 + h] = acc[r];
}

// ---------------------------------------------------------------- scatter-add messages
__global__ __launch_bounds__(256) void k_scatter(const float* __restrict__ y,
                                                 const int* __restrict__ src,
                                                 const int* __restrict__ dst,
                                                 const float* __restrict__ ew,
                                                 const float* __restrict__ lw,
                                                 const float* __restrict__ gate,
                                                 float* __restrict__ aggr,
                                                 int E, int nseg){
    int h = threadIdx.x & 63;
    int idx = blockIdx.x*4 + (threadIdx.x >> 6);
    int g = idx / E, e = idx % E;
    float gs = sigf(gate[0]);
    float mw = gs*ew[e] + (1.f-gs)*sigf(lw[e]);
    int s = src[e], d = dst[e];
    float v = mw * y[((size_t)g*nseg + s)*64 + h];
    atomicAdd(&aggr[((size_t)g*nseg + d)*64 + h], v);
}

// ---------------------------------------------------------------- u = relu(concat[aggr,x] @ Wu(128x64) + b)
template<int R, bool FN>
__global__ __launch_bounds__(64) void k_update(const float* __restrict__ aggr,
                                               const float* __restrict__ xin,
                                               const float* __restrict__ x,
                                               const float* __restrict__ Wu,
                                               const float* __restrict__ bu,
                                               float* __restrict__ u){
    __shared__ float ra[R][64], rx[R][64];
    int h = threadIdx.x;
    int r0 = blockIdx.x * R;
    for (int r=0;r<R;++r){
        int rr = r0 + r;
        ra[r][h] = aggr[(size_t)rr*64 + h];
        if (FN){
            int g = rr / NF_, j = rr % NF_;
            int b = g / T_, t = g % T_, n = j / F_, f = j % F_;
            rx[r][h] = x[((size_t)((b*N_+n)*F_+f)*T_ + t)*H_ + h];
        } else {
            rx[r][h] = xin[(size_t)rr*64 + h];
        }
    }
    __syncthreads();
    float acc[R];
    float bv = bu[h];
    #pragma unroll
    for (int r=0;r<R;++r) acc[r]=bv;
    for (int k=0;k<64;++k){
        float w = Wu[k*64+h];
        #pragma unroll
        for (int r=0;r<R;++r) acc[r] += ra[r][k]*w;
    }
    for (int k=0;k<64;++k){
        float w = Wu[(64+k)*64+h];
        #pragma unroll
        for (int r=0;r<R;++r) acc[r] += rx[r][k]*w;
    }
    for (int r=0;r<R;++r) u[(size_t)(r0+r)*64 + h] = fmaxf(acc[r], 0.f);
}

// ---------------------------------------------------------------- fusion MLP
template<int R>
__global__ __launch_bounds__(64) void k_fusion(const float* __restrict__ fnu,
                                               const float* __restrict__ wsu,
                                               const float* __restrict__ W1,
                                               const float* __restrict__ b1,
                                               const float* __restrict__ W2,
                                               const float* __restrict__ b2,
                                               float* __restrict__ fused){
    __shared__ float rf[R][64], rw[R][64], hid[R][64];
    int h = threadIdx.x;
    int r0 = blockIdx.x * R;
    for (int r=0;r<R;++r){
        int rr = r0 + r;           // g*NF + j
        int g = rr / NF_, j = rr % NF_;
        int n = j / F_;
        rf[r][h] = fnu[(size_t)rr*64 + h];
        rw[r][h] = wsu[((size_t)g*N_ + n)*64 + h];
    }
    __syncthreads();
    float acc[R];
    float bv = b1[h];
    #pragma unroll
    for (int r=0;r<R;++r) acc[r]=bv;
    for (int k=0;k<64;++k){
        float w = W1[k*64+h];
        #pragma unroll
        for (int r=0;r<R;++r) acc[r] += rf[r][k]*w;
    }
    for (int k=0;k<64;++k){
        float w = W1[(64+k)*64+h];
        #pragma unroll
        for (int r=0;r<R;++r) acc[r] += rw[r][k]*w;
    }
    for (int r=0;r<R;++r) hid[r][h] = fmaxf(acc[r], 0.f);
    __syncthreads();
    float acc2[R];
    float bv2 = b2[h];
    #pragma unroll
    for (int r=0;r<R;++r) acc2[r]=bv2;
    for (int k=0;k<64;++k){
        float w = W2[k*64+h];
        #pragma unroll
        for (int r=0;r<R;++r) acc2[r] += hid[r][k]*w;
    }
    for (int r=0;r<R;++r) fused[(size_t)(r0+r)*64 + h] = acc2[r];
}

// ---------------------------------------------------------------- transpose+cast transformer weights to bf16
// layout: wt[0..12287] = Wqkv^T [192][64]; +12288 Wo^T [64][64]; +16384 W1^T [256][64]; +32768 W2^T [64][256]
__global__ __launch_bounds__(256) void k_prepw(const float* __restrict__ Wqkv,
                                               const float* __restrict__ Wo,
                                               const float* __restrict__ W1,
                                               const float* __restrict__ W2,
                                               unsigned short* __restrict__ wt){
    int i = blockIdx.x*256 + threadIdx.x;
    if (i < 12288){ int n = i>>6, k = i&63; wt[i] = f2b(Wqkv[k*192+n]); }
    else if (i < 16384){ int z = i-12288; int n = z>>6, k = z&63; wt[i] = f2b(Wo[k*64+n]); }
    else if (i < 32768){ int z = i-16384; int n = z>>6, k = z&63; wt[i] = f2b(W1[k*256+n]); }
    else if (i < 49152){ int z = i-32768; int n = z>>8, k = z&255; wt[i] = f2b(W2[k*64+n]); }
}

// ---------------------------------------------------------------- MFMA temporal transformer
// 1 wave/block, 4 sequences/block, M-tile = 1 seq (12 rows padded to 16)
__global__ __launch_bounds__(64) void k_xformer(
    const float* __restrict__ fused,
    const unsigned short* __restrict__ wtq,   // [192][64] bf16  (n,k)
    const unsigned short* __restrict__ wto,   // [64][64]
    const unsigned short* __restrict__ wt1,   // [256][64]
    const unsigned short* __restrict__ wt2,   // [64][256]
    const float* __restrict__ bqkv, const float* __restrict__ bo,
    const float* __restrict__ fb1,  const float* __restrict__ fb2,
    const float* __restrict__ ln1g, const float* __restrict__ ln1b,
    const float* __restrict__ ln2g, const float* __restrict__ ln2b,
    float* __restrict__ out)
{
    __shared__ unsigned short XB[16*72];   // bf16 A-operand staging (stride 72)
    __shared__ float SC[16*204];           // f32 qkv scratch (stride 204); aliased as bf16 HID [16][264]
    unsigned short* HID = (unsigned short*)SC;

    int l  = threadIdx.x;
    int lr = l & 15;      // within-tile col index (MFMA index16)
    int lg = l >> 4;      // row group

    // hoisted LN params (per col)
    float g1[4], o1[4], g2[4], o2[4];
    #pragma unroll
    for (int nt=0;nt<4;++nt){
        g1[nt]=ln1g[nt*16+lr]; o1[nt]=ln1b[nt*16+lr];
        g2[nt]=ln2g[nt*16+lr]; o2[nt]=ln2b[nt*16+lr];
    }

    #pragma unroll 1
    for (int q=0;q<4;++q){
        int gs = blockIdx.x*4 + q;          // global row of output: (b*N+n)*F+f
        int bb = gs / NF_, j = gs % NF_;
        const float* fp = fused + ((size_t)bb*T_*NF_ + j)*64;   // + t*NF_*64 per t

        // ---- load input (C-layout) ----
        float res[4][4];
        #pragma unroll
        for (int nt=0;nt<4;++nt)
            #pragma unroll
            for (int i=0;i<4;++i){
                int t = lg*4+i;
                res[nt][i] = (t < 12) ? fp[(size_t)t*NF_*64 + nt*16 + lr] : 0.f;
            }

        // ---- LN1 -> XB (bf16) ----
        float mean[4], rst[4];
        {
            float sm[4], sq[4];
            #pragma unroll
            for (int i=0;i<4;++i){
                sm[i] = res[0][i]+res[1][i]+res[2][i]+res[3][i];
                sq[i] = res[0][i]*res[0][i]+res[1][i]*res[1][i]+res[2][i]*res[2][i]+res[3][i]*res[3][i];
            }
            #pragma unroll
            for (int m=1;m<16;m<<=1){
                #pragma unroll
                for (int i=0;i<4;++i){
                    sm[i] += __shfl_xor(sm[i], m, 64);
                    sq[i] += __shfl_xor(sq[i], m, 64);
                }
            }
            #pragma unroll
            for (int i=0;i<4;++i){
                mean[i] = sm[i]*(1.0f/64.0f);
                float var = sq[i]*(1.0f/64.0f) - mean[i]*mean[i];
                rst[i] = rsqrtf(var + 1e-5f);
            }
            #pragma unroll
            for (int nt=0;nt<4;++nt)
                #pragma unroll
                for (int i=0;i<4;++i){
                    int t = lg*4+i;
                    XB[t*72 + nt*16 + lr] = f2b((res[nt][i]-mean[i])*rst[i]*g1[nt] + o1[nt]);
                }
        }
        LGKM0;

        // ---- QKV GEMM: [16x64] @ [64x192] ----
        {
            bf16x8 a0 = *(const bf16x8*)&XB[lr*72 + 0*32 + lg*8];
            bf16x8 a1 = *(const bf16x8*)&XB[lr*72 + 1*32 + lg*8];
            f32x4 acc[12];
            #pragma unroll
            for (int ct=0;ct<12;++ct) acc[ct] = (f32x4){0.f,0.f,0.f,0.f};
            #pragma unroll
            for (int ct=0;ct<12;++ct){
                bf16x8 b0 = *(const bf16x8*)&wtq[(ct*16+lr)*64 + 0*32 + lg*8];
                bf16x8 b1v= *(const bf16x8*)&wtq[(ct*16+lr)*64 + 1*32 + lg*8];
                acc[ct] = __builtin_amdgcn_mfma_f32_16x16x32_bf16(a0, b0, acc[ct], 0,0,0);
                acc[ct] = __builtin_amdgcn_mfma_f32_16x16x32_bf16(a1, b1v, acc[ct], 0,0,0);
            }
            #pragma unroll
            for (int ct=0;ct<12;++ct){
                float bv = bqkv[ct*16+lr];
                #pragma unroll
                for (int i=0;i<4;++i)
                    SC[(lg*4+i)*204 + ct*16 + lr] = acc[ct][i] + bv;
            }
        }
        LGKM0;

        // ---- attention (vector, 48 lanes: head=l/12, qt=l%12) -> O into XB (bf16) ----
        if (l < 48){
            int hd = l/12, qt = l%12;
            float qv[16];
            #pragma unroll
            for (int d=0;d<16;++d) qv[d] = SC[qt*204 + hd*16 + d];
            float scv[12]; float mx = -1e30f;
            #pragma unroll
            for (int kt=0;kt<12;++kt){
                const float* kr = &SC[kt*204 + 64 + hd*16];
                float a = 0.f;
                #pragma unroll
                for (int d=0;d<16;++d) a += qv[d]*kr[d];
                a *= 0.25f;
                scv[kt] = a; mx = fmaxf(mx, a);
            }
            float den = 0.f;
            #pragma unroll
            for (int kt=0;kt<12;++kt){ scv[kt] = __expf(scv[kt]-mx); den += scv[kt]; }
            float inv = 1.0f/den;
            float ov[16];
            #pragma unroll
            for (int d=0;d<16;++d) ov[d]=0.f;
            #pragma unroll
            for (int kt=0;kt<12;++kt){
                float p = scv[kt];
                const float* vr = &SC[kt*204 + 128 + hd*16];
                #pragma unroll
                for (int d=0;d<16;++d) ov[d] += p*vr[d];
            }
            #pragma unroll
            for (int d=0;d<16;++d)
                XB[qt*72 + hd*16 + d] = f2b(ov[d]*inv);
        }
        LGKM0;

        // ---- proj + residual -> s1 ----
        float s1[4][4];
        {
            bf16x8 a0 = *(const bf16x8*)&XB[lr*72 + 0*32 + lg*8];
            bf16x8 a1 = *(const bf16x8*)&XB[lr*72 + 1*32 + lg*8];
            f32x4 pacc[4];
            #pragma unroll
            for (int ct=0;ct<4;++ct) pacc[ct] = (f32x4){0.f,0.f,0.f,0.f};
            #pragma unroll
            for (int ct=0;ct<4;++ct){
                bf16x8 b0 = *(const bf16x8*)&wto[(ct*16+lr)*64 + 0*32 + lg*8];
                bf16x8 b1v= *(const bf16x8*)&wto[(ct*16+lr)*64 + 1*32 + lg*8];
                pacc[ct] = __builtin_amdgcn_mfma_f32_16x16x32_bf16(a0, b0, pacc[ct], 0,0,0);
                pacc[ct] = __builtin_amdgcn_mfma_f32_16x16x32_bf16(a1, b1v, pacc[ct], 0,0,0);
            }
            #pragma unroll
            for (int ct=0;ct<4;++ct){
                float bv = bo[ct*16+lr];
                #pragma unroll
                for (int i=0;i<4;++i)
                    s1[ct][i] = res[ct][i] + pacc[ct][i] + bv;
            }
        }

        // ---- LN2 -> XB (bf16) ----
        {
            float sm[4], sq[4];
            #pragma unroll
            for (int i=0;i<4;++i){
                sm[i] = s1[0][i]+s1[1][i]+s1[2][i]+s1[3][i];
                sq[i] = s1[0][i]*s1[0][i]+s1[1][i]*s1[1][i]+s1[2][i]*s1[2][i]+s1[3][i]*s1[3][i];
            }
            #pragma unroll
            for (int m=1;m<16;m<<=1){
                #pragma unroll
                for (int i=0;i<4;++i){
                    sm[i] += __shfl_xor(sm[i], m, 64);
                    sq[i] += __shfl_xor(sq[i], m, 64);
                }
            }
            #pragma unroll
            for (int i=0;i<4;++i){
                float mn = sm[i]*(1.0f/64.0f);
                float var = sq[i]*(1.0f/64.0f) - mn*mn;
                float rs = rsqrtf(var + 1e-5f);
                mean[i] = mn; rst[i] = rs;
            }
            #pragma unroll
            for (int nt=0;nt<4;++nt)
                #pragma unroll
                for (int i=0;i<4;++i){
                    int t = lg*4+i;
                    XB[t*72 + nt*16 + lr] = f2b((s1[nt][i]-mean[i])*rst[i]*g2[nt] + o2[nt]);
                }
        }
        LGKM0;

        // ---- FFN1 [16x64]@[64x256] + gelu -> HID (bf16) ----
        {
            bf16x8 a0 = *(const bf16x8*)&XB[lr*72 + 0*32 + lg*8];
            bf16x8 a1 = *(const bf16x8*)&XB[lr*72 + 1*32 + lg*8];
            f32x4 facc[16];
            #pragma unroll
            for (int ct=0;ct<16;++ct) facc[ct] = (f32x4){0.f,0.f,0.f,0.f};
            #pragma unroll
            for (int ct=0;ct<16;++ct){
                bf16x8 b0 = *(const bf16x8*)&wt1[(ct*16+lr)*64 + 0*32 + lg*8];
                bf16x8 b1v= *(const bf16x8*)&wt1[(ct*16+lr)*64 + 1*32 + lg*8];
                facc[ct] = __builtin_amdgcn_mfma_f32_16x16x32_bf16(a0, b0, facc[ct], 0,0,0);
                facc[ct] = __builtin_amdgcn_mfma_f32_16x16x32_bf16(a1, b1v, facc[ct], 0,0,0);
            }
            #pragma unroll
            for (int ct=0;ct<16;++ct){
                float bv = fb1[ct*16+lr];
                #pragma unroll
                for (int i=0;i<4;++i){
                    float xv = facc[ct][i] + bv;
                    // tanh-approx gelu (max |err| ~2e-4 vs exact erf)
                    float u = 0.7978845608f*(xv + 0.044715f*xv*xv*xv);
                    float e = __expf(-2.0f*fabsf(u));
                    float th = (1.0f-e)/(1.0f+e);
                    th = (u < 0.f) ? -th : th;
                    HID[(lg*4+i)*264 + ct*16 + lr] = f2b(0.5f*xv*(1.0f+th));
                }
            }
        }
        LGKM0;

        // ---- FFN2 [16x256]@[256x64] + residual + mean over t ----
        {
            f32x4 oacc[4];
            #pragma unroll
            for (int ct=0;ct<4;++ct) oacc[ct] = (f32x4){0.f,0.f,0.f,0.f};
            #pragma unroll
            for (int ks=0;ks<8;++ks){
                bf16x8 af = *(const bf16x8*)&HID[lr*264 + ks*32 + lg*8];
                #pragma unroll
                for (int ct=0;ct<4;++ct){
                    bf16x8 bfr = *(const bf16x8*)&wt2[(ct*16+lr)*256 + ks*32 + lg*8];
                    oacc[ct] = __builtin_amdgcn_mfma_f32_16x16x32_bf16(af, bfr, oacc[ct], 0,0,0);
                }
            }
            #pragma unroll
            for (int ct=0;ct<4;++ct){
                float bv = fb2[ct*16+lr];
                float part = 0.f;
                #pragma unroll
                for (int i=0;i<4;++i){
                    if (lg*4+i < 12) part += s1[ct][i] + oacc[ct][i] + bv;
                }
                part += __shfl_xor(part, 16, 64);
                part += __shfl_xor(part, 32, 64);
                if (lg == 0) out[(size_t)gs*64 + ct*16 + lr] = part*(1.0f/12.0f);
            }
        }
        LGKM0;   // protect SC/XB reuse by next seq iteration
    }
}

// ----------------------------------------------------------------
extern "C" void kernel_launch(void* const* d_in, const int* in_sizes, int n_in,
                              void* d_out, int out_size, void* d_ws, size_t ws_size,
                              hipStream_t stream) {
    const float* x      = (const float*)d_in[0];
    const int*   r_ei   = (const int*)  d_in[1];
    const float* r_ea   = (const float*)d_in[2];
    const int*   c_ei   = (const int*)  d_in[3];
    const float* c_ew   = (const float*)d_in[4];
    const float* rvWlin = (const float*)d_in[5];
    const float* rvblin = (const float*)d_in[6];
    const float* rvWupd = (const float*)d_in[7];
    const float* rvbupd = (const float*)d_in[8];
    const float* rvgate = (const float*)d_in[9];
    const float* rvlw   = (const float*)d_in[10];
    const float* csWlin = (const float*)d_in[11];
    const float* csblin = (const float*)d_in[12];
    const float* csWupd = (const float*)d_in[13];
    const float* csbupd = (const float*)d_in[14];
    const float* csgate = (const float*)d_in[15];
    const float* cslw   = (const float*)d_in[16];
    const float* fuW1   = (const float*)d_in[17];
    const float* fub1   = (const float*)d_in[18];
    const float* fuW2   = (const float*)d_in[19];
    const float* fub2   = (const float*)d_in[20];
    const float* ln1g   = (const float*)d_in[21];
    const float* ln1b   = (const float*)d_in[22];
    const float* ln2g   = (const float*)d_in[23];
    const float* ln2b   = (const float*)d_in[24];
    const float* Wqkv   = (const float*)d_in[25];
    const float* bqkv   = (const float*)d_in[26];
    const float* Wo     = (const float*)d_in[27];
    const float* bo     = (const float*)d_in[28];
    const float* ffW1   = (const float*)d_in[29];
    const float* ffb1   = (const float*)d_in[30];
    const float* ffW2   = (const float*)d_in[31];
    const float* ffb2   = (const float*)d_in[32];

    float* wsp  = (float*)d_ws;
    float* FNY  = wsp;                               // 12,288,000  (later reused as FNU)
    float* FNA  = wsp + 12288000;                    // 12,288,000  (later reused as FUSED)
    float* WS   = wsp + 24576000;                    //  1,536,000
    float* WSY  = wsp + 26112000;                    //  1,536,000  (later reused for bf16 W^T)
    float* WSA  = wsp + 27648000;                    //  1,536,000
    float* WSU  = wsp + 29184000;                    //  1,536,000
    float* outp = (float*)d_out;

    unsigned short* wt = (unsigned short*)WSY;       // 49,152 bf16 (<< region size)

    hipMemsetAsync(FNA, 0, (size_t)12288000*sizeof(float), stream);
    hipMemsetAsync(WSA, 0, (size_t)1536000*sizeof(float), stream);

    // watershed repr
    k_ws<<<G_*N_, 64, 0, stream>>>(x, WS);
    // node linear transforms
    k_mm64<8,false><<<(G_*N_)/8, 64, 0, stream>>>(WS, nullptr, rvWlin, rvblin, WSY);
    k_mm64<8,true ><<<(G_*NF_)/8, 64, 0, stream>>>(nullptr, x, csWlin, csblin, FNY);
    // gated scatter-add
    k_scatter<<<(G_*ER_)/4, 256, 0, stream>>>(WSY, r_ei, r_ei+ER_, r_ea, rvlw, rvgate, WSA, ER_, N_);
    k_scatter<<<(G_*EC_)/4, 256, 0, stream>>>(FNY, c_ei, c_ei+EC_, c_ew, cslw, csgate, FNA, EC_, NF_);
    // WSY is dead from here: build bf16 transposed transformer weights into it
    k_prepw<<<192, 256, 0, stream>>>(Wqkv, Wo, ffW1, ffW2, wt);
    // update MLPs
    k_update<8,false><<<(G_*N_)/8, 64, 0, stream>>>(WSA, WS, nullptr, rvWupd, rvbupd, WSU);
    k_update<8,true ><<<(G_*NF_)/8, 64, 0, stream>>>(FNA, nullptr, x, csWupd, csbupd, FNY); // FNU = FNY
    // fusion (writes into FNA region = FUSED)
    k_fusion<8><<<(G_*NF_)/8, 64, 0, stream>>>(FNY, WSU, fuW1, fub1, fuW2, fub2, FNA);
    // MFMA temporal transformer + time-mean -> out
    k_xformer<<<(B_*N_*F_)/4, 64, 0, stream>>>(FNA,
                                               wt, wt+12288, wt+16384, wt+32768,
                                               bqkv, bo, ffb1, ffb2,
                                               ln1g, ln1b, ln2g, ln2b,
                                               outp);
}

// Round 4
// 601.346 us; speedup vs baseline: 1.7394x; 1.1302x over previous
//
#include <hip/hip_runtime.h>
#include <math.h>

#define B_ 2
#define N_ 1000
#define F_ 8
#define T_ 12
#define H_ 64
#define G_ 24      // B*T
#define NF_ 8000   // N*F
#define ER_ 2000
#define EC_ 24000

typedef short bf16x8 __attribute__((ext_vector_type(8)));
typedef float f32x4 __attribute__((ext_vector_type(4)));

#define LGKM0 do { asm volatile("s_waitcnt lgkmcnt(0)" ::: "memory"); __builtin_amdgcn_sched_barrier(0); } while(0)

__device__ __forceinline__ float sigf(float x){ return 1.0f/(1.0f+__expf(-x)); }

// f32 -> bf16 (RNE)
__device__ __forceinline__ unsigned short f2b(float f){
    unsigned u = __float_as_uint(f);
    unsigned r = (u + 0x7FFFu + ((u >> 16) & 1u)) >> 16;
    return (unsigned short)r;
}
__device__ __forceinline__ float b2f(unsigned short u){
    return __uint_as_float(((unsigned)u) << 16);
}

// ---------------------------------------------------------------- ws = mean over F
__global__ __launch_bounds__(64) void k_ws(const float* __restrict__ x, float* __restrict__ ws){
    int idx = blockIdx.x;            // g*N + n
    int h = threadIdx.x;
    int g = idx / N_, n = idx % N_;
    int b = g / T_, t = g % T_;
    const float* base = x + ((size_t)(b*N_+n)*F_*T_ + t)*H_ + h;
    float s = 0.f;
    #pragma unroll
    for (int f=0; f<F_; ++f) s += base[(size_t)f*T_*H_];
    ws[(size_t)idx*H_ + h] = s * (1.0f/F_);
}

// ---------------------------------------------------------------- y = xin @ W(64x64) + b   (LDS broadcast version)
template<int R, bool FN>
__global__ __launch_bounds__(64) void k_mm64(const float* __restrict__ xin,
                                             const float* __restrict__ x,
                                             const float* __restrict__ W,
                                             const float* __restrict__ bias,
                                             float* __restrict__ y){
    __shared__ float row[R][64];
    int h = threadIdx.x;
    int r0 = blockIdx.x * R;
    for (int r=0;r<R;++r){
        int rr = r0 + r;
        if (FN){
            int g = rr / NF_, j = rr % NF_;
            int b = g / T_, t = g % T_, n = j / F_, f = j % F_;
            row[r][h] = x[((size_t)((b*N_+n)*F_+f)*T_ + t)*H_ + h];
        } else {
            row[r][h] = xin[(size_t)rr*64 + h];
        }
    }
    __syncthreads();
    float acc[R];
    float bv = bias[h];
    #pragma unroll
    for (int r=0;r<R;++r) acc[r]=bv;
    for (int k=0;k<64;++k){
        float w = W[k*64+h];
        #pragma unroll
        for (int r=0;r<R;++r) acc[r] += row[r][k]*w;
    }
    for (int r=0;r<R;++r) y[(size_t)(r0+r)*64 + h] = acc[r];
}

// ---------------------------------------------------------------- scatter-add messages
__global__ __launch_bounds__(256) void k_scatter(const float* __restrict__ y,
                                                 const int* __restrict__ src,
                                                 const int* __restrict__ dst,
                                                 const float* __restrict__ ew,
                                                 const float* __restrict__ lw,
                                                 const float* __restrict__ gate,
                                                 float* __restrict__ aggr,
                                                 int E, int nseg){
    int h = threadIdx.x & 63;
    int idx = blockIdx.x*4 + (threadIdx.x >> 6);
    int g = idx / E, e = idx % E;
    float gs = sigf(gate[0]);
    float mw = gs*ew[e] + (1.f-gs)*sigf(lw[e]);
    int s = src[e], d = dst[e];
    float v = mw * y[((size_t)g*nseg + s)*64 + h];
    atomicAdd(&aggr[((size_t)g*nseg + d)*64 + h], v);
}

// ---------------------------------------------------------------- u = relu(concat[aggr,x] @ Wu(128x64) + b)
template<int R, bool FN>
__global__ __launch_bounds__(64) void k_update(const float* __restrict__ aggr,
                                               const float* __restrict__ xin,
                                               const float* __restrict__ x,
                                               const float* __restrict__ Wu,
                                               const float* __restrict__ bu,
                                               float* __restrict__ u){
    __shared__ float ra[R][64], rx[R][64];
    int h = threadIdx.x;
    int r0 = blockIdx.x * R;
    for (int r=0;r<R;++r){
        int rr = r0 + r;
        ra[r][h] = aggr[(size_t)rr*64 + h];
        if (FN){
            int g = rr / NF_, j = rr % NF_;
            int b = g / T_, t = g % T_, n = j / F_, f = j % F_;
            rx[r][h] = x[((size_t)((b*N_+n)*F_+f)*T_ + t)*H_ + h];
        } else {
            rx[r][h] = xin[(size_t)rr*64 + h];
        }
    }
    __syncthreads();
    float acc[R];
    float bv = bu[h];
    #pragma unroll
    for (int r=0;r<R;++r) acc[r]=bv;
    for (int k=0;k<64;++k){
        float w = Wu[k*64+h];
        #pragma unroll
        for (int r=0;r<R;++r) acc[r] += ra[r][k]*w;
    }
    for (int k=0;k<64;++k){
        float w = Wu[(64+k)*64+h];
        #pragma unroll
        for (int r=0;r<R;++r) acc[r] += rx[r][k]*w;
    }
    for (int r=0;r<R;++r) u[(size_t)(r0+r)*64 + h] = fmaxf(acc[r], 0.f);
}

// ---------------------------------------------------------------- fusion MLP
template<int R>
__global__ __launch_bounds__(64) void k_fusion(const float* __restrict__ fnu,
                                               const float* __restrict__ wsu,
                                               const float* __restrict__ W1,
                                               const float* __restrict__ b1,
                                               const float* __restrict__ W2,
                                               const float* __restrict__ b2,
                                               float* __restrict__ fused){
    __shared__ float rf[R][64], rw[R][64], hid[R][64];
    int h = threadIdx.x;
    int r0 = blockIdx.x * R;
    for (int r=0;r<R;++r){
        int rr = r0 + r;           // g*NF + j
        int g = rr / NF_, j = rr % NF_;
        int n = j / F_;
        rf[r][h] = fnu[(size_t)rr*64 + h];
        rw[r][h] = wsu[((size_t)g*N_ + n)*64 + h];
    }
    __syncthreads();
    float acc[R];
    float bv = b1[h];
    #pragma unroll
    for (int r=0;r<R;++r) acc[r]=bv;
    for (int k=0;k<64;++k){
        float w = W1[k*64+h];
        #pragma unroll
        for (int r=0;r<R;++r) acc[r] += rf[r][k]*w;
    }
    for (int k=0;k<64;++k){
        float w = W1[(64+k)*64+h];
        #pragma unroll
        for (int r=0;r<R;++r) acc[r] += rw[r][k]*w;
    }
    for (int r=0;r<R;++r) hid[r][h] = fmaxf(acc[r], 0.f);
    __syncthreads();
    float acc2[R];
    float bv2 = b2[h];
    #pragma unroll
    for (int r=0;r<R;++r) acc2[r]=bv2;
    for (int k=0;k<64;++k){
        float w = W2[k*64+h];
        #pragma unroll
        for (int r=0;r<R;++r) acc2[r] += hid[r][k]*w;
    }
    for (int r=0;r<R;++r) fused[(size_t)(r0+r)*64 + h] = acc2[r];
}

// ---------------------------------------------------------------- transpose+cast transformer weights to bf16
// layout: wt[0..12287] = Wqkv^T [192][64]; +12288 Wo^T [64][64]; +16384 W1^T [256][64]; +32768 W2^T [64][256]
__global__ __launch_bounds__(256) void k_prepw(const float* __restrict__ Wqkv,
                                               const float* __restrict__ Wo,
                                               const float* __restrict__ W1,
                                               const float* __restrict__ W2,
                                               unsigned short* __restrict__ wt){
    int i = blockIdx.x*256 + threadIdx.x;
    if (i < 12288){ int n = i>>6, k = i&63; wt[i] = f2b(Wqkv[k*192+n]); }
    else if (i < 16384){ int z = i-12288; int n = z>>6, k = z&63; wt[i] = f2b(Wo[k*64+n]); }
    else if (i < 32768){ int z = i-16384; int n = z>>6, k = z&63; wt[i] = f2b(W1[k*256+n]); }
    else if (i < 49152){ int z = i-32768; int n = z>>8, k = z&255; wt[i] = f2b(W2[k*64+n]); }
}

// ---------------------------------------------------------------- MFMA temporal transformer
// 256 threads = 4 waves/block; each wave owns ONE sequence with private LDS slice.
#define XSTR 72    // XB stride (bf16): A-operand staging
#define QSTR 200   // SC stride (bf16): QKV scratch (192 cols + pad)
#define HSTR 136   // HID stride (bf16): FFN half-hidden (128 cols + pad), 272B = 16B-aligned

__global__ __launch_bounds__(256,4) void k_xformer(
    const float* __restrict__ fused,
    const unsigned short* __restrict__ wtq,   // [192][64] bf16  (n,k)
    const unsigned short* __restrict__ wto,   // [64][64]
    const unsigned short* __restrict__ wt1,   // [256][64]
    const unsigned short* __restrict__ wt2,   // [64][256]
    const float* __restrict__ bqkv, const float* __restrict__ bo,
    const float* __restrict__ fb1,  const float* __restrict__ fb2,
    const float* __restrict__ ln1g, const float* __restrict__ ln1b,
    const float* __restrict__ ln2g, const float* __restrict__ ln2b,
    float* __restrict__ out)
{
    __shared__ unsigned short XBs[4][16*XSTR];   // per-wave A staging
    __shared__ unsigned short SCs[4][16*QSTR];   // per-wave QKV scratch / FFN HID (aliased)

    int w  = threadIdx.x >> 6;
    int l  = threadIdx.x & 63;
    int lr = l & 15;      // MFMA index16
    int lg = l >> 4;      // row group

    unsigned short* XB  = XBs[w];
    unsigned short* SC  = SCs[w];
    unsigned short* HID = SCs[w];    // FFN half-hidden reuses SC (QKV dead by then)

    // hoisted LN params (per col)
    float g1[4], o1[4], g2[4], o2[4];
    #pragma unroll
    for (int nt=0;nt<4;++nt){
        g1[nt]=ln1g[nt*16+lr]; o1[nt]=ln1b[nt*16+lr];
        g2[nt]=ln2g[nt*16+lr]; o2[nt]=ln2b[nt*16+lr];
    }

    int gs = blockIdx.x*4 + w;          // global row of output: (b*N+n)*F+f
    int bb = gs / NF_, j = gs % NF_;
    const float* fp = fused + ((size_t)bb*T_*NF_ + j)*64;   // + t*NF_*64 per t

    // ---- load input (C-layout): res[nt][i] = seq[t=lg*4+i][nt*16+lr] ----
    float res[4][4];
    #pragma unroll
    for (int nt=0;nt<4;++nt)
        #pragma unroll
        for (int i=0;i<4;++i){
            int t = lg*4+i;
            res[nt][i] = (t < 12) ? fp[(size_t)t*NF_*64 + nt*16 + lr] : 0.f;
        }

    // ---- LN1 -> XB (bf16) ----
    {
        float sm[4], sq[4];
        #pragma unroll
        for (int i=0;i<4;++i){
            sm[i] = res[0][i]+res[1][i]+res[2][i]+res[3][i];
            sq[i] = res[0][i]*res[0][i]+res[1][i]*res[1][i]+res[2][i]*res[2][i]+res[3][i]*res[3][i];
        }
        #pragma unroll
        for (int m=1;m<16;m<<=1){
            #pragma unroll
            for (int i=0;i<4;++i){
                sm[i] += __shfl_xor(sm[i], m, 64);
                sq[i] += __shfl_xor(sq[i], m, 64);
            }
        }
        #pragma unroll
        for (int i=0;i<4;++i){
            float mn = sm[i]*(1.0f/64.0f);
            float var = sq[i]*(1.0f/64.0f) - mn*mn;
            float rs = rsqrtf(var + 1e-5f);
            #pragma unroll
            for (int nt=0;nt<4;++nt)
                XB[(lg*4+i)*XSTR + nt*16 + lr] = f2b((res[nt][i]-mn)*rs*g1[nt] + o1[nt]);
        }
    }
    LGKM0;

    // ---- QKV GEMM: [16x64] @ [64x192] -> SC (bf16) ----
    {
        bf16x8 a0 = *(const bf16x8*)&XB[lr*XSTR + 0*32 + lg*8];
        bf16x8 a1 = *(const bf16x8*)&XB[lr*XSTR + 1*32 + lg*8];
        f32x4 acc[12];
        #pragma unroll
        for (int ct=0;ct<12;++ct) acc[ct] = (f32x4){0.f,0.f,0.f,0.f};
        #pragma unroll
        for (int ct=0;ct<12;++ct){
            bf16x8 b0 = *(const bf16x8*)&wtq[(ct*16+lr)*64 + 0*32 + lg*8];
            bf16x8 b1v= *(const bf16x8*)&wtq[(ct*16+lr)*64 + 1*32 + lg*8];
            acc[ct] = __builtin_amdgcn_mfma_f32_16x16x32_bf16(a0, b0, acc[ct], 0,0,0);
            acc[ct] = __builtin_amdgcn_mfma_f32_16x16x32_bf16(a1, b1v, acc[ct], 0,0,0);
        }
        #pragma unroll
        for (int ct=0;ct<12;++ct){
            float bv = bqkv[ct*16+lr];
            #pragma unroll
            for (int i=0;i<4;++i)
                SC[(lg*4+i)*QSTR + ct*16 + lr] = f2b(acc[ct][i] + bv);
        }
    }
    LGKM0;

    // ---- attention (vector, 48 lanes: head=l/12, qt=l%12) -> O into XB (bf16) ----
    if (l < 48){
        int hd = l/12, qt = l%12;
        float qv[16];
        {
            bf16x8 q0 = *(const bf16x8*)&SC[qt*QSTR + hd*16];
            bf16x8 q1 = *(const bf16x8*)&SC[qt*QSTR + hd*16 + 8];
            #pragma unroll
            for (int d=0;d<8;++d){ qv[d] = b2f((unsigned short)q0[d]); qv[8+d] = b2f((unsigned short)q1[d]); }
        }
        float scv[12]; float mx = -1e30f;
        #pragma unroll
        for (int kt=0;kt<12;++kt){
            bf16x8 k0 = *(const bf16x8*)&SC[kt*QSTR + 64 + hd*16];
            bf16x8 k1 = *(const bf16x8*)&SC[kt*QSTR + 64 + hd*16 + 8];
            float a = 0.f;
            #pragma unroll
            for (int d=0;d<8;++d){
                a += qv[d]  *b2f((unsigned short)k0[d]);
                a += qv[8+d]*b2f((unsigned short)k1[d]);
            }
            a *= 0.25f;
            scv[kt] = a; mx = fmaxf(mx, a);
        }
        float den = 0.f;
        #pragma unroll
        for (int kt=0;kt<12;++kt){ scv[kt] = __expf(scv[kt]-mx); den += scv[kt]; }
        float inv = 1.0f/den;
        float ov[16];
        #pragma unroll
        for (int d=0;d<16;++d) ov[d]=0.f;
        #pragma unroll
        for (int kt=0;kt<12;++kt){
            float p = scv[kt];
            bf16x8 v0 = *(const bf16x8*)&SC[kt*QSTR + 128 + hd*16];
            bf16x8 v1 = *(const bf16x8*)&SC[kt*QSTR + 128 + hd*16 + 8];
            #pragma unroll
            for (int d=0;d<8;++d){
                ov[d]   += p*b2f((unsigned short)v0[d]);
                ov[8+d] += p*b2f((unsigned short)v1[d]);
            }
        }
        bf16x8 s0, s1v;
        #pragma unroll
        for (int d=0;d<8;++d){ s0[d] = (short)f2b(ov[d]*inv); s1v[d] = (short)f2b(ov[8+d]*inv); }
        *(bf16x8*)&XB[qt*XSTR + hd*16]     = s0;
        *(bf16x8*)&XB[qt*XSTR + hd*16 + 8] = s1v;
    }
    LGKM0;

    // ---- proj + residual -> s1 (overwrites res) ----
    float s1[4][4];
    {
        bf16x8 a0 = *(const bf16x8*)&XB[lr*XSTR + 0*32 + lg*8];
        bf16x8 a1 = *(const bf16x8*)&XB[lr*XSTR + 1*32 + lg*8];
        f32x4 pacc[4];
        #pragma unroll
        for (int ct=0;ct<4;++ct) pacc[ct] = (f32x4){0.f,0.f,0.f,0.f};
        #pragma unroll
        for (int ct=0;ct<4;++ct){
            bf16x8 b0 = *(const bf16x8*)&wto[(ct*16+lr)*64 + 0*32 + lg*8];
            bf16x8 b1v= *(const bf16x8*)&wto[(ct*16+lr)*64 + 1*32 + lg*8];
            pacc[ct] = __builtin_amdgcn_mfma_f32_16x16x32_bf16(a0, b0, pacc[ct], 0,0,0);
            pacc[ct] = __builtin_amdgcn_mfma_f32_16x16x32_bf16(a1, b1v, pacc[ct], 0,0,0);
        }
        #pragma unroll
        for (int ct=0;ct<4;++ct){
            float bv = bo[ct*16+lr];
            #pragma unroll
            for (int i=0;i<4;++i)
                s1[ct][i] = res[ct][i] + pacc[ct][i] + bv;
        }
    }

    // ---- LN2 -> XB (bf16) ----
    {
        float sm[4], sq[4];
        #pragma unroll
        for (int i=0;i<4;++i){
            sm[i] = s1[0][i]+s1[1][i]+s1[2][i]+s1[3][i];
            sq[i] = s1[0][i]*s1[0][i]+s1[1][i]*s1[1][i]+s1[2][i]*s1[2][i]+s1[3][i]*s1[3][i];
        }
        #pragma unroll
        for (int m=1;m<16;m<<=1){
            #pragma unroll
            for (int i=0;i<4;++i){
                sm[i] += __shfl_xor(sm[i], m, 64);
                sq[i] += __shfl_xor(sq[i], m, 64);
            }
        }
        #pragma unroll
        for (int i=0;i<4;++i){
            float mn = sm[i]*(1.0f/64.0f);
            float var = sq[i]*(1.0f/64.0f) - mn*mn;
            float rs = rsqrtf(var + 1e-5f);
            #pragma unroll
            for (int nt=0;nt<4;++nt)
                XB[(lg*4+i)*XSTR + nt*16 + lr] = f2b((s1[nt][i]-mn)*rs*g2[nt] + o2[nt]);
        }
    }
    LGKM0;

    // ---- FFN in two 128-wide halves: FFN1-half + gelu -> HID, then FFN2 accumulate ----
    f32x4 oacc[4];
    #pragma unroll
    for (int ct=0;ct<4;++ct) oacc[ct] = (f32x4){0.f,0.f,0.f,0.f};
    {
        bf16x8 a0 = *(const bf16x8*)&XB[lr*XSTR + 0*32 + lg*8];
        bf16x8 a1 = *(const bf16x8*)&XB[lr*XSTR + 1*32 + lg*8];
        #pragma unroll
        for (int half=0; half<2; ++half){
            LGKM0;   // HID region reuse guard (half 1 must not overwrite before half 0 reads land)
            f32x4 facc[8];
            #pragma unroll
            for (int c=0;c<8;++c) facc[c] = (f32x4){0.f,0.f,0.f,0.f};
            #pragma unroll
            for (int c=0;c<8;++c){
                int ct = half*8 + c;
                bf16x8 b0 = *(const bf16x8*)&wt1[(ct*16+lr)*64 + 0*32 + lg*8];
                bf16x8 b1v= *(const bf16x8*)&wt1[(ct*16+lr)*64 + 1*32 + lg*8];
                facc[c] = __builtin_amdgcn_mfma_f32_16x16x32_bf16(a0, b0, facc[c], 0,0,0);
                facc[c] = __builtin_amdgcn_mfma_f32_16x16x32_bf16(a1, b1v, facc[c], 0,0,0);
            }
            #pragma unroll
            for (int c=0;c<8;++c){
                int ct = half*8 + c;
                float bv = fb1[ct*16+lr];
                #pragma unroll
                for (int i=0;i<4;++i){
                    float xv = facc[c][i] + bv;
                    // tanh-approx gelu (max |err| ~3e-4 vs exact erf)
                    float u = 0.7978845608f*(xv + 0.044715f*xv*xv*xv);
                    float e = __expf(-2.0f*fabsf(u));
                    float th = (1.0f-e)/(1.0f+e);
                    th = (u < 0.f) ? -th : th;
                    HID[(lg*4+i)*HSTR + c*16 + lr] = f2b(0.5f*xv*(1.0f+th));
                }
            }
            LGKM0;
            #pragma unroll
            for (int ks=0;ks<4;++ks){
                bf16x8 af = *(const bf16x8*)&HID[lr*HSTR + ks*32 + lg*8];
                #pragma unroll
                for (int ct=0;ct<4;++ct){
                    bf16x8 bfr = *(const bf16x8*)&wt2[(ct*16+lr)*256 + half*128 + ks*32 + lg*8];
                    oacc[ct] = __builtin_amdgcn_mfma_f32_16x16x32_bf16(af, bfr, oacc[ct], 0,0,0);
                }
            }
        }
    }

    // ---- residual + mean over t ----
    #pragma unroll
    for (int ct=0;ct<4;++ct){
        float bv = fb2[ct*16+lr];
        float part = 0.f;
        #pragma unroll
        for (int i=0;i<4;++i){
            if (lg*4+i < 12) part += s1[ct][i] + oacc[ct][i] + bv;
        }
        part += __shfl_xor(part, 16, 64);
        part += __shfl_xor(part, 32, 64);
        if (lg == 0) out[(size_t)gs*64 + ct*16 + lr] = part*(1.0f/12.0f);
    }
}

// ----------------------------------------------------------------
extern "C" void kernel_launch(void* const* d_in, const int* in_sizes, int n_in,
                              void* d_out, int out_size, void* d_ws, size_t ws_size,
                              hipStream_t stream) {
    const float* x      = (const float*)d_in[0];
    const int*   r_ei   = (const int*)  d_in[1];
    const float* r_ea   = (const float*)d_in[2];
    const int*   c_ei   = (const int*)  d_in[3];
    const float* c_ew   = (const float*)d_in[4];
    const float* rvWlin = (const float*)d_in[5];
    const float* rvblin = (const float*)d_in[6];
    const float* rvWupd = (const float*)d_in[7];
    const float* rvbupd = (const float*)d_in[8];
    const float* rvgate = (const float*)d_in[9];
    const float* rvlw   = (const float*)d_in[10];
    const float* csWlin = (const float*)d_in[11];
    const float* csblin = (const float*)d_in[12];
    const float* csWupd = (const float*)d_in[13];
    const float* csbupd = (const float*)d_in[14];
    const float* csgate = (const float*)d_in[15];
    const float* cslw   = (const float*)d_in[16];
    const float* fuW1   = (const float*)d_in[17];
    const float* fub1   = (const float*)d_in[18];
    const float* fuW2   = (const float*)d_in[19];
    const float* fub2   = (const float*)d_in[20];
    const float* ln1g   = (const float*)d_in[21];
    const float* ln1b   = (const float*)d_in[22];
    const float* ln2g   = (const float*)d_in[23];
    const float* ln2b   = (const float*)d_in[24];
    const float* Wqkv   = (const float*)d_in[25];
    const float* bqkv   = (const float*)d_in[26];
    const float* Wo     = (const float*)d_in[27];
    const float* bo     = (const float*)d_in[28];
    const float* ffW1   = (const float*)d_in[29];
    const float* ffb1   = (const float*)d_in[30];
    const float* ffW2   = (const float*)d_in[31];
    const float* ffb2   = (const float*)d_in[32];

    float* wsp  = (float*)d_ws;
    float* FNY  = wsp;                               // 12,288,000  (later reused as FNU)
    float* FNA  = wsp + 12288000;                    // 12,288,000  (later reused as FUSED)
    float* WS   = wsp + 24576000;                    //  1,536,000
    float* WSY  = wsp + 26112000;                    //  1,536,000  (later reused for bf16 W^T)
    float* WSA  = wsp + 27648000;                    //  1,536,000
    float* WSU  = wsp + 29184000;                    //  1,536,000
    float* outp = (float*)d_out;

    unsigned short* wt = (unsigned short*)WSY;       // 49,152 bf16 (<< region size)

    hipMemsetAsync(FNA, 0, (size_t)12288000*sizeof(float), stream);
    hipMemsetAsync(WSA, 0, (size_t)1536000*sizeof(float), stream);

    // watershed repr
    k_ws<<<G_*N_, 64, 0, stream>>>(x, WS);
    // node linear transforms
    k_mm64<8,false><<<(G_*N_)/8, 64, 0, stream>>>(WS, nullptr, rvWlin, rvblin, WSY);
    k_mm64<8,true ><<<(G_*NF_)/8, 64, 0, stream>>>(nullptr, x, csWlin, csblin, FNY);
    // gated scatter-add
    k_scatter<<<(G_*ER_)/4, 256, 0, stream>>>(WSY, r_ei, r_ei+ER_, r_ea, rvlw, rvgate, WSA, ER_, N_);
    k_scatter<<<(G_*EC_)/4, 256, 0, stream>>>(FNY, c_ei, c_ei+EC_, c_ew, cslw, csgate, FNA, EC_, NF_);
    // WSY is dead from here: build bf16 transposed transformer weights into it
    k_prepw<<<192, 256, 0, stream>>>(Wqkv, Wo, ffW1, ffW2, wt);
    // update MLPs
    k_update<8,false><<<(G_*N_)/8, 64, 0, stream>>>(WSA, WS, nullptr, rvWupd, rvbupd, WSU);
    k_update<8,true ><<<(G_*NF_)/8, 64, 0, stream>>>(FNA, nullptr, x, csWupd, csbupd, FNY); // FNU = FNY
    // fusion (writes into FNA region = FUSED)
    k_fusion<8><<<(G_*NF_)/8, 64, 0, stream>>>(FNY, WSU, fuW1, fub1, fuW2, fub2, FNA);
    // MFMA temporal transformer + time-mean -> out
    k_xformer<<<(B_*N_*F_)/4, 256, 0, stream>>>(FNA,
                                                wt, wt+12288, wt+16384, wt+32768,
                                                bqkv, bo, ffb1, ffb2,
                                                ln1g, ln1b, ln2g, ln2b,
                                                outp);
}

// Round 5
// 536.050 us; speedup vs baseline: 1.9512x; 1.1218x over previous
//
#include <hip/hip_runtime.h>
#include <math.h>

#define B_ 2
#define N_ 1000
#define F_ 8
#define T_ 12
#define H_ 64
#define G_ 24      // B*T
#define NF_ 8000   // N*F
#define ER_ 2000
#define EC_ 24000

typedef short bf16x8 __attribute__((ext_vector_type(8)));
typedef float f32x4 __attribute__((ext_vector_type(4)));

#define LGKM0 do { asm volatile("s_waitcnt lgkmcnt(0)" ::: "memory"); __builtin_amdgcn_sched_barrier(0); } while(0)

__device__ __forceinline__ float sigf(float x){ return 1.0f/(1.0f+__expf(-x)); }

// f32 -> bf16 (RNE)
__device__ __forceinline__ unsigned short f2b(float f){
    unsigned u = __float_as_uint(f);
    unsigned r = (u + 0x7FFFu + ((u >> 16) & 1u)) >> 16;
    return (unsigned short)r;
}
__device__ __forceinline__ float b2f(unsigned short u){
    return __uint_as_float(((unsigned)u) << 16);
}

// ---------------------------------------------------------------- ws = mean over F
__global__ __launch_bounds__(64) void k_ws(const float* __restrict__ x, float* __restrict__ ws){
    int idx = blockIdx.x;            // g*N + n
    int h = threadIdx.x;
    int g = idx / N_, n = idx % N_;
    int b = g / T_, t = g % T_;
    const float* base = x + ((size_t)(b*N_+n)*F_*T_ + t)*H_ + h;
    float s = 0.f;
    #pragma unroll
    for (int f=0; f<F_; ++f) s += base[(size_t)f*T_*H_];
    ws[(size_t)idx*H_ + h] = s * (1.0f/F_);
}

// ---------------------------------------------------------------- scatter-add messages
__global__ __launch_bounds__(256) void k_scatter(const float* __restrict__ y,
                                                 const int* __restrict__ src,
                                                 const int* __restrict__ dst,
                                                 const float* __restrict__ ew,
                                                 const float* __restrict__ lw,
                                                 const float* __restrict__ gate,
                                                 float* __restrict__ aggr,
                                                 int E, int nseg){
    int h = threadIdx.x & 63;
    int idx = blockIdx.x*4 + (threadIdx.x >> 6);
    int g = idx / E, e = idx % E;
    float gs = sigf(gate[0]);
    float mw = gs*ew[e] + (1.f-gs)*sigf(lw[e]);
    int s = src[e], d = dst[e];
    float v = mw * y[((size_t)g*nseg + s)*64 + h];
    atomicAdd(&aggr[((size_t)g*nseg + d)*64 + h], v);
}

// ---------------------------------------------------------------- weight prep: bf16 W^T panels
// shorts offsets: 0 wtq[192][64] | 12288 wto[64][64] | 16384 wt1[256][64] | 32768 wt2[64][256]
// 49152 csWlinT[64][64] | 53248 rvWlinT[64][64] | 57344 csWupdT[64][128] | 65536 rvWupdT[64][128]
// 73728 fuW1T[64][128] | 81920 fuW2T[64][64] | end 86016
__global__ __launch_bounds__(256) void k_prepw(const float* __restrict__ Wqkv,
                                               const float* __restrict__ Wo,
                                               const float* __restrict__ W1,
                                               const float* __restrict__ W2,
                                               const float* __restrict__ csWlin,
                                               const float* __restrict__ rvWlin,
                                               const float* __restrict__ csWupd,
                                               const float* __restrict__ rvWupd,
                                               const float* __restrict__ fuW1,
                                               const float* __restrict__ fuW2,
                                               unsigned short* __restrict__ wt){
    int i = blockIdx.x*256 + threadIdx.x;
    if      (i < 12288){ int n=i>>6, k=i&63; wt[i] = f2b(Wqkv[k*192+n]); }
    else if (i < 16384){ int z=i-12288; int n=z>>6, k=z&63; wt[i] = f2b(Wo[k*64+n]); }
    else if (i < 32768){ int z=i-16384; int n=z>>6, k=z&63; wt[i] = f2b(W1[k*256+n]); }
    else if (i < 49152){ int z=i-32768; int n=z>>8, k=z&255; wt[i] = f2b(W2[k*64+n]); }
    else if (i < 53248){ int z=i-49152; int n=z>>6, k=z&63; wt[i] = f2b(csWlin[k*64+n]); }
    else if (i < 57344){ int z=i-53248; int n=z>>6, k=z&63; wt[i] = f2b(rvWlin[k*64+n]); }
    else if (i < 65536){ int z=i-57344; int n=z>>7, k=z&127; wt[i] = f2b(csWupd[k*64+n]); }
    else if (i < 73728){ int z=i-65536; int n=z>>7, k=z&127; wt[i] = f2b(rvWupd[k*64+n]); }
    else if (i < 81920){ int z=i-73728; int n=z>>7, k=z&127; wt[i] = f2b(fuW1[k*64+n]); }
    else if (i < 86016){ int z=i-81920; int n=z>>6, k=z&63; wt[i] = f2b(fuW2[k*64+n]); }
}

// ---------------------------------------------------------------- MFMA y = rows @ W(64x64) + b
// 4 waves/block, 16 rows/wave. GATHER: rows from x as fn[g, j]; else linear xin.
template<bool GATHER>
__global__ __launch_bounds__(256) void k_lin16(const float* __restrict__ xin,
                                               const float* __restrict__ x,
                                               const unsigned short* __restrict__ wT,  // [64 n][64 k]
                                               const float* __restrict__ bias,
                                               float* __restrict__ y){
    __shared__ unsigned short XBs[4][16*72];
    int w = threadIdx.x>>6, l = threadIdx.x&63;
    int lr = l&15, lg = l>>4;
    unsigned short* XB = XBs[w];
    int r0 = (blockIdx.x*4 + w)*16;
    #pragma unroll
    for (int i=0;i<16;++i){
        int rr = r0+i;
        float v;
        if (GATHER){
            int g = rr/NF_, j = rr%NF_;
            int b = g/T_, t = g%T_, n = j/F_, f = j%F_;
            v = x[((size_t)((b*N_+n)*F_+f)*T_ + t)*64 + l];
        } else {
            v = xin[(size_t)rr*64 + l];
        }
        XB[i*72 + l] = f2b(v);
    }
    LGKM0;
    bf16x8 a0 = *(const bf16x8*)&XB[lr*72 + lg*8];
    bf16x8 a1 = *(const bf16x8*)&XB[lr*72 + 32 + lg*8];
    f32x4 acc[4];
    #pragma unroll
    for (int ct=0;ct<4;++ct) acc[ct] = (f32x4){0.f,0.f,0.f,0.f};
    #pragma unroll
    for (int ct=0;ct<4;++ct){
        bf16x8 b0 = *(const bf16x8*)&wT[(ct*16+lr)*64 + lg*8];
        bf16x8 b1 = *(const bf16x8*)&wT[(ct*16+lr)*64 + 32 + lg*8];
        acc[ct] = __builtin_amdgcn_mfma_f32_16x16x32_bf16(a0, b0, acc[ct], 0,0,0);
        acc[ct] = __builtin_amdgcn_mfma_f32_16x16x32_bf16(a1, b1, acc[ct], 0,0,0);
    }
    #pragma unroll
    for (int ct=0;ct<4;++ct){
        float bv = bias[ct*16+lr];
        #pragma unroll
        for (int i=0;i<4;++i)
            y[(size_t)(r0+lg*4+i)*64 + ct*16+lr] = acc[ct][i] + bv;
    }
}

// ---------------------------------------------------------------- MFMA u = relu([aggr|src] @ Wu(128x64) + b)
template<bool GATHER>
__global__ __launch_bounds__(256) void k_upd16(const float* __restrict__ aggr,
                                               const float* __restrict__ xin,
                                               const float* __restrict__ x,
                                               const unsigned short* __restrict__ wT,  // [64 n][128 k]
                                               const float* __restrict__ bu,
                                               float* __restrict__ u){
    __shared__ unsigned short XBs[4][16*136];
    int w = threadIdx.x>>6, l = threadIdx.x&63;
    int lr = l&15, lg = l>>4;
    unsigned short* XB = XBs[w];
    int r0 = (blockIdx.x*4 + w)*16;
    #pragma unroll
    for (int i=0;i<16;++i){
        int rr = r0+i;
        XB[i*136 + l] = f2b(aggr[(size_t)rr*64 + l]);
        float v;
        if (GATHER){
            int g = rr/NF_, j = rr%NF_;
            int b = g/T_, t = g%T_, n = j/F_, f = j%F_;
            v = x[((size_t)((b*N_+n)*F_+f)*T_ + t)*64 + l];
        } else {
            v = xin[(size_t)rr*64 + l];
        }
        XB[i*136 + 64 + l] = f2b(v);
    }
    LGKM0;
    bf16x8 a[4];
    #pragma unroll
    for (int kk=0;kk<4;++kk) a[kk] = *(const bf16x8*)&XB[lr*136 + kk*32 + lg*8];
    f32x4 acc[4];
    #pragma unroll
    for (int ct=0;ct<4;++ct) acc[ct] = (f32x4){0.f,0.f,0.f,0.f};
    #pragma unroll
    for (int ct=0;ct<4;++ct){
        #pragma unroll
        for (int kk=0;kk<4;++kk){
            bf16x8 b0 = *(const bf16x8*)&wT[(ct*16+lr)*128 + kk*32 + lg*8];
            acc[ct] = __builtin_amdgcn_mfma_f32_16x16x32_bf16(a[kk], b0, acc[ct], 0,0,0);
        }
    }
    #pragma unroll
    for (int ct=0;ct<4;++ct){
        float bv = bu[ct*16+lr];
        #pragma unroll
        for (int i=0;i<4;++i)
            u[(size_t)(r0+lg*4+i)*64 + ct*16+lr] = fmaxf(acc[ct][i] + bv, 0.f);
    }
}

// ---------------------------------------------------------------- MFMA fusion: relu([fnu|wsu]@W1(128x64)+b1)@W2(64x64)+b2
__global__ __launch_bounds__(256) void k_fus16(const float* __restrict__ fnu,
                                               const float* __restrict__ wsu,
                                               const unsigned short* __restrict__ w1T,  // [64][128]
                                               const float* __restrict__ b1,
                                               const unsigned short* __restrict__ w2T,  // [64][64]
                                               const float* __restrict__ b2,
                                               float* __restrict__ fused){
    __shared__ unsigned short XBs[4][16*136];
    __shared__ unsigned short HIDs[4][16*72];
    int w = threadIdx.x>>6, l = threadIdx.x&63;
    int lr = l&15, lg = l>>4;
    unsigned short* XB  = XBs[w];
    unsigned short* HID = HIDs[w];
    int r0 = (blockIdx.x*4 + w)*16;
    #pragma unroll
    for (int i=0;i<16;++i){
        int rr = r0+i;                 // g*NF + j
        int g = rr/NF_, n = (rr%NF_)/F_;
        XB[i*136 + l]      = f2b(fnu[(size_t)rr*64 + l]);
        XB[i*136 + 64 + l] = f2b(wsu[((size_t)g*N_ + n)*64 + l]);
    }
    LGKM0;
    bf16x8 a[4];
    #pragma unroll
    for (int kk=0;kk<4;++kk) a[kk] = *(const bf16x8*)&XB[lr*136 + kk*32 + lg*8];
    f32x4 acc[4];
    #pragma unroll
    for (int ct=0;ct<4;++ct) acc[ct] = (f32x4){0.f,0.f,0.f,0.f};
    #pragma unroll
    for (int ct=0;ct<4;++ct){
        #pragma unroll
        for (int kk=0;kk<4;++kk){
            bf16x8 b0 = *(const bf16x8*)&w1T[(ct*16+lr)*128 + kk*32 + lg*8];
            acc[ct] = __builtin_amdgcn_mfma_f32_16x16x32_bf16(a[kk], b0, acc[ct], 0,0,0);
        }
    }
    #pragma unroll
    for (int ct=0;ct<4;++ct){
        float bv = b1[ct*16+lr];
        #pragma unroll
        for (int i=0;i<4;++i)
            HID[(lg*4+i)*72 + ct*16+lr] = f2b(fmaxf(acc[ct][i] + bv, 0.f));
    }
    LGKM0;
    bf16x8 h0 = *(const bf16x8*)&HID[lr*72 + lg*8];
    bf16x8 h1 = *(const bf16x8*)&HID[lr*72 + 32 + lg*8];
    f32x4 acc2[4];
    #pragma unroll
    for (int ct=0;ct<4;++ct) acc2[ct] = (f32x4){0.f,0.f,0.f,0.f};
    #pragma unroll
    for (int ct=0;ct<4;++ct){
        bf16x8 b0 = *(const bf16x8*)&w2T[(ct*16+lr)*64 + lg*8];
        bf16x8 b1v= *(const bf16x8*)&w2T[(ct*16+lr)*64 + 32 + lg*8];
        acc2[ct] = __builtin_amdgcn_mfma_f32_16x16x32_bf16(h0, b0, acc2[ct], 0,0,0);
        acc2[ct] = __builtin_amdgcn_mfma_f32_16x16x32_bf16(h1, b1v, acc2[ct], 0,0,0);
    }
    #pragma unroll
    for (int ct=0;ct<4;++ct){
        float bv = b2[ct*16+lr];
        #pragma unroll
        for (int i=0;i<4;++i)
            fused[(size_t)(r0+lg*4+i)*64 + ct*16+lr] = acc2[ct][i] + bv;
    }
}

// ---------------------------------------------------------------- MFMA temporal transformer
// 256 threads = 4 waves/block; each wave owns ONE sequence with private LDS slice.
#define XSTR 72    // XB stride (bf16): A-operand staging, 16 rows
#define QSTR 200   // SC stride (bf16): QKV scratch, 12 rows (192 cols + pad, 400B = 16B-aligned)
#define HSTR 136   // HID stride (bf16): FFN half-hidden, 16 rows (fits in 12*200 region)

__global__ __launch_bounds__(256,5) void k_xformer(
    const float* __restrict__ fused,
    const unsigned short* __restrict__ wtq,   // [192][64] bf16  (n,k)
    const unsigned short* __restrict__ wto,   // [64][64]
    const unsigned short* __restrict__ wt1,   // [256][64]
    const unsigned short* __restrict__ wt2,   // [64][256]
    const float* __restrict__ bqkv, const float* __restrict__ bo,
    const float* __restrict__ fb1,  const float* __restrict__ fb2,
    const float* __restrict__ ln1g, const float* __restrict__ ln1b,
    const float* __restrict__ ln2g, const float* __restrict__ ln2b,
    float* __restrict__ out)
{
    __shared__ unsigned short XBs[4][16*XSTR];   // per-wave A staging
    __shared__ unsigned short SCs[4][12*QSTR];   // per-wave QKV scratch / FFN HID (aliased)

    int w  = threadIdx.x >> 6;
    int l  = threadIdx.x & 63;
    int lr = l & 15;      // MFMA index16
    int lg = l >> 4;      // row group

    unsigned short* XB  = XBs[w];
    unsigned short* SC  = SCs[w];
    unsigned short* HID = SCs[w];    // FFN half-hidden reuses SC (QKV dead by then); 16*136 <= 12*200

    // hoisted LN params (per col)
    float g1[4], o1[4], g2[4], o2[4];
    #pragma unroll
    for (int nt=0;nt<4;++nt){
        g1[nt]=ln1g[nt*16+lr]; o1[nt]=ln1b[nt*16+lr];
        g2[nt]=ln2g[nt*16+lr]; o2[nt]=ln2b[nt*16+lr];
    }

    int gs = blockIdx.x*4 + w;          // global row of output: (b*N+n)*F+f
    int bb = gs / NF_, j = gs % NF_;
    const float* fp = fused + ((size_t)bb*T_*NF_ + j)*64;   // + t*NF_*64 per t

    // ---- load input (C-layout): res[nt][i] = seq[t=lg*4+i][nt*16+lr] ----
    float res[4][4];
    #pragma unroll
    for (int nt=0;nt<4;++nt)
        #pragma unroll
        for (int i=0;i<4;++i){
            int t = lg*4+i;
            res[nt][i] = (t < 12) ? fp[(size_t)t*NF_*64 + nt*16 + lr] : 0.f;
        }

    // ---- LN1 -> XB (bf16) ----
    {
        float sm[4], sq[4];
        #pragma unroll
        for (int i=0;i<4;++i){
            sm[i] = res[0][i]+res[1][i]+res[2][i]+res[3][i];
            sq[i] = res[0][i]*res[0][i]+res[1][i]*res[1][i]+res[2][i]*res[2][i]+res[3][i]*res[3][i];
        }
        #pragma unroll
        for (int m=1;m<16;m<<=1){
            #pragma unroll
            for (int i=0;i<4;++i){
                sm[i] += __shfl_xor(sm[i], m, 64);
                sq[i] += __shfl_xor(sq[i], m, 64);
            }
        }
        #pragma unroll
        for (int i=0;i<4;++i){
            float mn = sm[i]*(1.0f/64.0f);
            float var = sq[i]*(1.0f/64.0f) - mn*mn;
            float rs = rsqrtf(var + 1e-5f);
            #pragma unroll
            for (int nt=0;nt<4;++nt)
                XB[(lg*4+i)*XSTR + nt*16 + lr] = f2b((res[nt][i]-mn)*rs*g1[nt] + o1[nt]);
        }
    }
    LGKM0;

    // ---- QKV GEMM: [16x64] @ [64x192] -> SC (bf16, 12 rows) ----
    {
        bf16x8 a0 = *(const bf16x8*)&XB[lr*XSTR + 0*32 + lg*8];
        bf16x8 a1 = *(const bf16x8*)&XB[lr*XSTR + 1*32 + lg*8];
        f32x4 acc[12];
        #pragma unroll
        for (int ct=0;ct<12;++ct) acc[ct] = (f32x4){0.f,0.f,0.f,0.f};
        #pragma unroll
        for (int ct=0;ct<12;++ct){
            bf16x8 b0 = *(const bf16x8*)&wtq[(ct*16+lr)*64 + 0*32 + lg*8];
            bf16x8 b1v= *(const bf16x8*)&wtq[(ct*16+lr)*64 + 1*32 + lg*8];
            acc[ct] = __builtin_amdgcn_mfma_f32_16x16x32_bf16(a0, b0, acc[ct], 0,0,0);
            acc[ct] = __builtin_amdgcn_mfma_f32_16x16x32_bf16(a1, b1v, acc[ct], 0,0,0);
        }
        #pragma unroll
        for (int ct=0;ct<12;++ct){
            float bv = bqkv[ct*16+lr];
            #pragma unroll
            for (int i=0;i<4;++i){
                int t = lg*4+i;
                if (t < 12) SC[t*QSTR + ct*16 + lr] = f2b(acc[ct][i] + bv);
            }
        }
    }
    LGKM0;

    // ---- attention (vector, 48 lanes: head=l/12, qt=l%12) -> O into XB (bf16) ----
    if (l < 48){
        int hd = l/12, qt = l%12;
        float qv[16];
        {
            bf16x8 q0 = *(const bf16x8*)&SC[qt*QSTR + hd*16];
            bf16x8 q1 = *(const bf16x8*)&SC[qt*QSTR + hd*16 + 8];
            #pragma unroll
            for (int d=0;d<8;++d){ qv[d] = b2f((unsigned short)q0[d]); qv[8+d] = b2f((unsigned short)q1[d]); }
        }
        float scv[12]; float mx = -1e30f;
        #pragma unroll
        for (int kt=0;kt<12;++kt){
            bf16x8 k0 = *(const bf16x8*)&SC[kt*QSTR + 64 + hd*16];
            bf16x8 k1 = *(const bf16x8*)&SC[kt*QSTR + 64 + hd*16 + 8];
            float a = 0.f;
            #pragma unroll
            for (int d=0;d<8;++d){
                a += qv[d]  *b2f((unsigned short)k0[d]);
                a += qv[8+d]*b2f((unsigned short)k1[d]);
            }
            a *= 0.25f;
            scv[kt] = a; mx = fmaxf(mx, a);
        }
        float den = 0.f;
        #pragma unroll
        for (int kt=0;kt<12;++kt){ scv[kt] = __expf(scv[kt]-mx); den += scv[kt]; }
        float inv = 1.0f/den;
        float ov[16];
        #pragma unroll
        for (int d=0;d<16;++d) ov[d]=0.f;
        #pragma unroll
        for (int kt=0;kt<12;++kt){
            float p = scv[kt];
            bf16x8 v0 = *(const bf16x8*)&SC[kt*QSTR + 128 + hd*16];
            bf16x8 v1 = *(const bf16x8*)&SC[kt*QSTR + 128 + hd*16 + 8];
            #pragma unroll
            for (int d=0;d<8;++d){
                ov[d]   += p*b2f((unsigned short)v0[d]);
                ov[8+d] += p*b2f((unsigned short)v1[d]);
            }
        }
        bf16x8 s0, s1v;
        #pragma unroll
        for (int d=0;d<8;++d){ s0[d] = (short)f2b(ov[d]*inv); s1v[d] = (short)f2b(ov[8+d]*inv); }
        *(bf16x8*)&XB[qt*XSTR + hd*16]     = s0;
        *(bf16x8*)&XB[qt*XSTR + hd*16 + 8] = s1v;
    }
    LGKM0;

    // ---- proj + residual -> s1 ----
    float s1[4][4];
    {
        bf16x8 a0 = *(const bf16x8*)&XB[lr*XSTR + 0*32 + lg*8];
        bf16x8 a1 = *(const bf16x8*)&XB[lr*XSTR + 1*32 + lg*8];
        f32x4 pacc[4];
        #pragma unroll
        for (int ct=0;ct<4;++ct) pacc[ct] = (f32x4){0.f,0.f,0.f,0.f};
        #pragma unroll
        for (int ct=0;ct<4;++ct){
            bf16x8 b0 = *(const bf16x8*)&wto[(ct*16+lr)*64 + 0*32 + lg*8];
            bf16x8 b1v= *(const bf16x8*)&wto[(ct*16+lr)*64 + 1*32 + lg*8];
            pacc[ct] = __builtin_amdgcn_mfma_f32_16x16x32_bf16(a0, b0, pacc[ct], 0,0,0);
            pacc[ct] = __builtin_amdgcn_mfma_f32_16x16x32_bf16(a1, b1v, pacc[ct], 0,0,0);
        }
        #pragma unroll
        for (int ct=0;ct<4;++ct){
            float bv = bo[ct*16+lr];
            #pragma unroll
            for (int i=0;i<4;++i)
                s1[ct][i] = res[ct][i] + pacc[ct][i] + bv;
        }
    }

    // ---- LN2 -> XB (bf16) ----
    {
        float sm[4], sq[4];
        #pragma unroll
        for (int i=0;i<4;++i){
            sm[i] = s1[0][i]+s1[1][i]+s1[2][i]+s1[3][i];
            sq[i] = s1[0][i]*s1[0][i]+s1[1][i]*s1[1][i]+s1[2][i]*s1[2][i]+s1[3][i]*s1[3][i];
        }
        #pragma unroll
        for (int m=1;m<16;m<<=1){
            #pragma unroll
            for (int i=0;i<4;++i){
                sm[i] += __shfl_xor(sm[i], m, 64);
                sq[i] += __shfl_xor(sq[i], m, 64);
            }
        }
        #pragma unroll
        for (int i=0;i<4;++i){
            float mn = sm[i]*(1.0f/64.0f);
            float var = sq[i]*(1.0f/64.0f) - mn*mn;
            float rs = rsqrtf(var + 1e-5f);
            #pragma unroll
            for (int nt=0;nt<4;++nt)
                XB[(lg*4+i)*XSTR + nt*16 + lr] = f2b((s1[nt][i]-mn)*rs*g2[nt] + o2[nt]);
        }
    }
    LGKM0;

    // ---- FFN in two 128-wide halves: FFN1-half + gelu -> HID, then FFN2 accumulate ----
    f32x4 oacc[4];
    #pragma unroll
    for (int ct=0;ct<4;++ct) oacc[ct] = (f32x4){0.f,0.f,0.f,0.f};
    {
        bf16x8 a0 = *(const bf16x8*)&XB[lr*XSTR + 0*32 + lg*8];
        bf16x8 a1 = *(const bf16x8*)&XB[lr*XSTR + 1*32 + lg*8];
        #pragma unroll
        for (int half=0; half<2; ++half){
            LGKM0;   // HID region reuse guard
            f32x4 facc[8];
            #pragma unroll
            for (int c=0;c<8;++c) facc[c] = (f32x4){0.f,0.f,0.f,0.f};
            #pragma unroll
            for (int c=0;c<8;++c){
                int ct = half*8 + c;
                bf16x8 b0 = *(const bf16x8*)&wt1[(ct*16+lr)*64 + 0*32 + lg*8];
                bf16x8 b1v= *(const bf16x8*)&wt1[(ct*16+lr)*64 + 1*32 + lg*8];
                facc[c] = __builtin_amdgcn_mfma_f32_16x16x32_bf16(a0, b0, facc[c], 0,0,0);
                facc[c] = __builtin_amdgcn_mfma_f32_16x16x32_bf16(a1, b1v, facc[c], 0,0,0);
            }
            #pragma unroll
            for (int c=0;c<8;++c){
                int ct = half*8 + c;
                float bv = fb1[ct*16+lr];
                #pragma unroll
                for (int i=0;i<4;++i){
                    float xv = facc[c][i] + bv;
                    // tanh-approx gelu (max |err| ~3e-4 vs exact erf)
                    float u = 0.7978845608f*(xv + 0.044715f*xv*xv*xv);
                    float e = __expf(-2.0f*fabsf(u));
                    float th = (1.0f-e)/(1.0f+e);
                    th = (u < 0.f) ? -th : th;
                    HID[(lg*4+i)*HSTR + c*16 + lr] = f2b(0.5f*xv*(1.0f+th));
                }
            }
            LGKM0;
            #pragma unroll
            for (int ks=0;ks<4;++ks){
                bf16x8 af = *(const bf16x8*)&HID[lr*HSTR + ks*32 + lg*8];
                #pragma unroll
                for (int ct=0;ct<4;++ct){
                    bf16x8 bfr = *(const bf16x8*)&wt2[(ct*16+lr)*256 + half*128 + ks*32 + lg*8];
                    oacc[ct] = __builtin_amdgcn_mfma_f32_16x16x32_bf16(af, bfr, oacc[ct], 0,0,0);
                }
            }
        }
    }

    // ---- residual + mean over t ----
    #pragma unroll
    for (int ct=0;ct<4;++ct){
        float bv = fb2[ct*16+lr];
        float part = 0.f;
        #pragma unroll
        for (int i=0;i<4;++i){
            if (lg*4+i < 12) part += s1[ct][i] + oacc[ct][i] + bv;
        }
        part += __shfl_xor(part, 16, 64);
        part += __shfl_xor(part, 32, 64);
        if (lg == 0) out[(size_t)gs*64 + ct*16 + lr] = part*(1.0f/12.0f);
    }
}

// ----------------------------------------------------------------
extern "C" void kernel_launch(void* const* d_in, const int* in_sizes, int n_in,
                              void* d_out, int out_size, void* d_ws, size_t ws_size,
                              hipStream_t stream) {
    const float* x      = (const float*)d_in[0];
    const int*   r_ei   = (const int*)  d_in[1];
    const float* r_ea   = (const float*)d_in[2];
    const int*   c_ei   = (const int*)  d_in[3];
    const float* c_ew   = (const float*)d_in[4];
    const float* rvWlin = (const float*)d_in[5];
    const float* rvblin = (const float*)d_in[6];
    const float* rvWupd = (const float*)d_in[7];
    const float* rvbupd = (const float*)d_in[8];
    const float* rvgate = (const float*)d_in[9];
    const float* rvlw   = (const float*)d_in[10];
    const float* csWlin = (const float*)d_in[11];
    const float* csblin = (const float*)d_in[12];
    const float* csWupd = (const float*)d_in[13];
    const float* csbupd = (const float*)d_in[14];
    const float* csgate = (const float*)d_in[15];
    const float* cslw   = (const float*)d_in[16];
    const float* fuW1   = (const float*)d_in[17];
    const float* fub1   = (const float*)d_in[18];
    const float* fuW2   = (const float*)d_in[19];
    const float* fub2   = (const float*)d_in[20];
    const float* ln1g   = (const float*)d_in[21];
    const float* ln1b   = (const float*)d_in[22];
    const float* ln2g   = (const float*)d_in[23];
    const float* ln2b   = (const float*)d_in[24];
    const float* Wqkv   = (const float*)d_in[25];
    const float* bqkv   = (const float*)d_in[26];
    const float* Wo     = (const float*)d_in[27];
    const float* bo     = (const float*)d_in[28];
    const float* ffW1   = (const float*)d_in[29];
    const float* ffb1   = (const float*)d_in[30];
    const float* ffW2   = (const float*)d_in[31];
    const float* ffb2   = (const float*)d_in[32];

    float* wsp  = (float*)d_ws;
    float* FNY  = wsp;                               // 12,288,000  (later reused as FNU)
    float* FNA  = wsp + 12288000;                    // 12,288,000  (later reused as FUSED)
    float* WS   = wsp + 24576000;                    //  1,536,000
    float* WSY  = wsp + 26112000;                    //  1,536,000
    float* WSA  = wsp + 27648000;                    //  1,536,000
    float* WSU  = wsp + 29184000;                    //  1,536,000
    unsigned short* wt = (unsigned short*)(wsp + 30720000);   // 86,016 bf16 = 172 KB
    float* outp = (float*)d_out;

    hipMemsetAsync(FNA, 0, (size_t)12288000*sizeof(float), stream);
    hipMemsetAsync(WSA, 0, (size_t)1536000*sizeof(float), stream);

    // bf16 transposed weight panels (all GEMM weights)
    k_prepw<<<336, 256, 0, stream>>>(Wqkv, Wo, ffW1, ffW2, csWlin, rvWlin, csWupd, rvWupd,
                                     fuW1, fuW2, wt);
    // watershed repr
    k_ws<<<G_*N_, 64, 0, stream>>>(x, WS);
    // node linear transforms (MFMA)
    k_lin16<false><<<(G_*N_)/64, 256, 0, stream>>>(WS, nullptr, wt+53248, rvblin, WSY);
    k_lin16<true ><<<(G_*NF_)/64, 256, 0, stream>>>(nullptr, x, wt+49152, csblin, FNY);
    // gated scatter-add
    k_scatter<<<(G_*ER_)/4, 256, 0, stream>>>(WSY, r_ei, r_ei+ER_, r_ea, rvlw, rvgate, WSA, ER_, N_);
    k_scatter<<<(G_*EC_)/4, 256, 0, stream>>>(FNY, c_ei, c_ei+EC_, c_ew, cslw, csgate, FNA, EC_, NF_);
    // update MLPs (MFMA)
    k_upd16<false><<<(G_*N_)/64, 256, 0, stream>>>(WSA, WS, nullptr, wt+65536, rvbupd, WSU);
    k_upd16<true ><<<(G_*NF_)/64, 256, 0, stream>>>(FNA, nullptr, x, wt+57344, csbupd, FNY); // FNU = FNY
    // fusion (MFMA; writes into FNA region = FUSED)
    k_fus16<<<(G_*NF_)/64, 256, 0, stream>>>(FNY, WSU, wt+73728, fub1, wt+81920, fub2, FNA);
    // MFMA temporal transformer + time-mean -> out
    k_xformer<<<(B_*N_*F_)/4, 256, 0, stream>>>(FNA,
                                                wt, wt+12288, wt+16384, wt+32768,
                                                bqkv, bo, ffb1, ffb2,
                                                ln1g, ln1b, ln2g, ln2b,
                                                outp);
}

// Round 6
// 454.473 us; speedup vs baseline: 2.3015x; 1.1795x over previous
//
#include <hip/hip_runtime.h>
#include <math.h>

#define B_ 2
#define N_ 1000
#define F_ 8
#define T_ 12
#define H_ 64
#define G_ 24      // B*T
#define NF_ 8000   // N*F
#define ER_ 2000
#define EC_ 24000

typedef short bf16x8 __attribute__((ext_vector_type(8)));
typedef float f32x4 __attribute__((ext_vector_type(4)));

#define LGKM0 do { asm volatile("s_waitcnt lgkmcnt(0)" ::: "memory"); __builtin_amdgcn_sched_barrier(0); } while(0)

__device__ __forceinline__ float sigf(float x){ return 1.0f/(1.0f+__expf(-x)); }

// f32 -> bf16 (RNE)
__device__ __forceinline__ unsigned short f2b(float f){
    unsigned u = __float_as_uint(f);
    unsigned r = (u + 0x7FFFu + ((u >> 16) & 1u)) >> 16;
    return (unsigned short)r;
}
__device__ __forceinline__ float b2f(unsigned short u){
    return __uint_as_float(((unsigned)u) << 16);
}

// ---------------------------------------------------------------- ws = mean over F
__global__ __launch_bounds__(64) void k_ws(const float* __restrict__ x, float* __restrict__ ws){
    int idx = blockIdx.x;            // g*N + n
    int h = threadIdx.x;
    int g = idx / N_, n = idx % N_;
    int b = g / T_, t = g % T_;
    const float* base = x + ((size_t)(b*N_+n)*F_*T_ + t)*H_ + h;
    float s = 0.f;
    #pragma unroll
    for (int f=0; f<F_; ++f) s += base[(size_t)f*T_*H_];
    ws[(size_t)idx*H_ + h] = s * (1.0f/F_);
}

// ---------------------------------------------------------------- CSR build: mw + histogram
__global__ __launch_bounds__(256) void k_mwhist(const int* __restrict__ c_dst, const int* __restrict__ r_dst,
                                                const float* __restrict__ c_ew, const float* __restrict__ c_lw,
                                                const float* __restrict__ c_gate,
                                                const float* __restrict__ r_ew, const float* __restrict__ r_lw,
                                                const float* __restrict__ r_gate,
                                                float* __restrict__ mw_c, float* __restrict__ mw_r,
                                                int* __restrict__ cnt_c, int* __restrict__ cnt_r){
    int i = blockIdx.x*256 + threadIdx.x;
    if (i < EC_){
        float gs = sigf(c_gate[0]);
        mw_c[i] = gs*c_ew[i] + (1.f-gs)*sigf(c_lw[i]);
        atomicAdd(&cnt_c[c_dst[i]], 1);
    } else if (i < EC_+ER_){
        int e = i - EC_;
        float gs = sigf(r_gate[0]);
        mw_r[e] = gs*r_ew[e] + (1.f-gs)*sigf(r_lw[e]);
        atomicAdd(&cnt_r[r_dst[e]], 1);
    }
}

// ---------------------------------------------------------------- CSR build: exclusive scan (block 0: causal, block 1: river)
__global__ __launch_bounds__(256) void k_scan(const int* __restrict__ cnt_c, int* __restrict__ off_c, int* __restrict__ cur_c,
                                              const int* __restrict__ cnt_r, int* __restrict__ off_r, int* __restrict__ cur_r){
    const int n = (blockIdx.x==0) ? NF_ : N_;
    const int* cnt = (blockIdx.x==0) ? cnt_c : cnt_r;
    int* off = (blockIdx.x==0) ? off_c : off_r;
    int* cur = (blockIdx.x==0) ? cur_c : cur_r;
    __shared__ int part[256];
    int tid = threadIdx.x;
    int tpt = (n + 255) / 256;
    int i0 = tid * tpt;
    int s = 0;
    for (int i=0;i<tpt;++i){ int idx=i0+i; if (idx<n) s += cnt[idx]; }
    part[tid] = s;
    __syncthreads();
    if (tid == 0){
        int run = 0;
        for (int j=0;j<256;++j){ int t = part[j]; part[j] = run; run += t; }
        off[n] = run;
    }
    __syncthreads();
    int run = part[tid];
    for (int i=0;i<tpt;++i){
        int idx = i0+i;
        if (idx < n){ off[idx] = run; cur[idx] = run; run += cnt[idx]; }
    }
}

// ---------------------------------------------------------------- CSR build: fill edge lists
__global__ __launch_bounds__(256) void k_fill(const int* __restrict__ c_dst, const int* __restrict__ r_dst,
                                              int* __restrict__ cur_c, int* __restrict__ cur_r,
                                              int* __restrict__ eidx_c, int* __restrict__ eidx_r){
    int i = blockIdx.x*256 + threadIdx.x;
    if (i < EC_){
        int p = atomicAdd(&cur_c[c_dst[i]], 1);
        eidx_c[p] = i;
    } else if (i < EC_+ER_){
        int e = i - EC_;
        int p = atomicAdd(&cur_r[r_dst[e]], 1);
        eidx_r[p] = e;
    }
}

// ---------------------------------------------------------------- gather-aggregate: one wave per (g,dst), no atomics
__global__ __launch_bounds__(256) void k_gaggr(const float* __restrict__ y,
                                               const int* __restrict__ src,
                                               const int* __restrict__ eidx,
                                               const int* __restrict__ off,
                                               const float* __restrict__ mw,
                                               float* __restrict__ aggr,
                                               int nseg, int cpx){
    int l = threadIdx.x & 63;
    // XCD-chunked swizzle: keep each graph's y-slab in one XCD's L2
    int wg = (blockIdx.x & 7)*cpx + (blockIdx.x >> 3);
    int idx = wg*4 + (threadIdx.x >> 6);   // g*nseg + d
    int g = idx / nseg, d = idx % nseg;
    int o0 = off[d], o1 = off[d+1];
    float acc = 0.f;
    for (int p=o0; p<o1; ++p){
        int e = eidx[p];
        acc += mw[e] * y[((size_t)g*nseg + src[e])*64 + l];
    }
    aggr[(size_t)idx*64 + l] = acc;
}

// ---------------------------------------------------------------- weight prep: bf16 W^T panels
// shorts offsets: 0 wtq[192][64] | 12288 wto[64][64] | 16384 wt1[256][64] | 32768 wt2[64][256]
// 49152 csWlinT[64][64] | 53248 rvWlinT[64][64] | 57344 csWupdT[64][128] | 65536 rvWupdT[64][128]
// 73728 fuW1T[64][128] | 81920 fuW2T[64][64] | end 86016
__global__ __launch_bounds__(256) void k_prepw(const float* __restrict__ Wqkv,
                                               const float* __restrict__ Wo,
                                               const float* __restrict__ W1,
                                               const float* __restrict__ W2,
                                               const float* __restrict__ csWlin,
                                               const float* __restrict__ rvWlin,
                                               const float* __restrict__ csWupd,
                                               const float* __restrict__ rvWupd,
                                               const float* __restrict__ fuW1,
                                               const float* __restrict__ fuW2,
                                               unsigned short* __restrict__ wt){
    int i = blockIdx.x*256 + threadIdx.x;
    if      (i < 12288){ int n=i>>6, k=i&63; wt[i] = f2b(Wqkv[k*192+n]); }
    else if (i < 16384){ int z=i-12288; int n=z>>6, k=z&63; wt[i] = f2b(Wo[k*64+n]); }
    else if (i < 32768){ int z=i-16384; int n=z>>6, k=z&63; wt[i] = f2b(W1[k*256+n]); }
    else if (i < 49152){ int z=i-32768; int n=z>>8, k=z&255; wt[i] = f2b(W2[k*64+n]); }
    else if (i < 53248){ int z=i-49152; int n=z>>6, k=z&63; wt[i] = f2b(csWlin[k*64+n]); }
    else if (i < 57344){ int z=i-53248; int n=z>>6, k=z&63; wt[i] = f2b(rvWlin[k*64+n]); }
    else if (i < 65536){ int z=i-57344; int n=z>>7, k=z&127; wt[i] = f2b(csWupd[k*64+n]); }
    else if (i < 73728){ int z=i-65536; int n=z>>7, k=z&127; wt[i] = f2b(rvWupd[k*64+n]); }
    else if (i < 81920){ int z=i-73728; int n=z>>7, k=z&127; wt[i] = f2b(fuW1[k*64+n]); }
    else if (i < 86016){ int z=i-81920; int n=z>>6, k=z&63; wt[i] = f2b(fuW2[k*64+n]); }
}

// ---------------------------------------------------------------- MFMA y = rows @ W(64x64) + b
template<bool GATHER>
__global__ __launch_bounds__(256) void k_lin16(const float* __restrict__ xin,
                                               const float* __restrict__ x,
                                               const unsigned short* __restrict__ wT,  // [64 n][64 k]
                                               const float* __restrict__ bias,
                                               float* __restrict__ y){
    __shared__ unsigned short XBs[4][16*72];
    int w = threadIdx.x>>6, l = threadIdx.x&63;
    int lr = l&15, lg = l>>4;
    unsigned short* XB = XBs[w];
    int r0 = (blockIdx.x*4 + w)*16;
    #pragma unroll
    for (int i=0;i<16;++i){
        int rr = r0+i;
        float v;
        if (GATHER){
            int g = rr/NF_, j = rr%NF_;
            int b = g/T_, t = g%T_, n = j/F_, f = j%F_;
            v = x[((size_t)((b*N_+n)*F_+f)*T_ + t)*64 + l];
        } else {
            v = xin[(size_t)rr*64 + l];
        }
        XB[i*72 + l] = f2b(v);
    }
    LGKM0;
    bf16x8 a0 = *(const bf16x8*)&XB[lr*72 + lg*8];
    bf16x8 a1 = *(const bf16x8*)&XB[lr*72 + 32 + lg*8];
    f32x4 acc[4];
    #pragma unroll
    for (int ct=0;ct<4;++ct) acc[ct] = (f32x4){0.f,0.f,0.f,0.f};
    #pragma unroll
    for (int ct=0;ct<4;++ct){
        bf16x8 b0 = *(const bf16x8*)&wT[(ct*16+lr)*64 + lg*8];
        bf16x8 b1 = *(const bf16x8*)&wT[(ct*16+lr)*64 + 32 + lg*8];
        acc[ct] = __builtin_amdgcn_mfma_f32_16x16x32_bf16(a0, b0, acc[ct], 0,0,0);
        acc[ct] = __builtin_amdgcn_mfma_f32_16x16x32_bf16(a1, b1, acc[ct], 0,0,0);
    }
    #pragma unroll
    for (int ct=0;ct<4;++ct){
        float bv = bias[ct*16+lr];
        #pragma unroll
        for (int i=0;i<4;++i)
            y[(size_t)(r0+lg*4+i)*64 + ct*16+lr] = acc[ct][i] + bv;
    }
}

// ---------------------------------------------------------------- MFMA u = relu([aggr|src] @ Wu(128x64) + b)  (river)
__global__ __launch_bounds__(256) void k_upd16(const float* __restrict__ aggr,
                                               const float* __restrict__ xin,
                                               const unsigned short* __restrict__ wT,  // [64 n][128 k]
                                               const float* __restrict__ bu,
                                               float* __restrict__ u){
    __shared__ unsigned short XBs[4][16*136];
    int w = threadIdx.x>>6, l = threadIdx.x&63;
    int lr = l&15, lg = l>>4;
    unsigned short* XB = XBs[w];
    int r0 = (blockIdx.x*4 + w)*16;
    #pragma unroll
    for (int i=0;i<16;++i){
        int rr = r0+i;
        XB[i*136 + l]      = f2b(aggr[(size_t)rr*64 + l]);
        XB[i*136 + 64 + l] = f2b(xin[(size_t)rr*64 + l]);
    }
    LGKM0;
    bf16x8 a[4];
    #pragma unroll
    for (int kk=0;kk<4;++kk) a[kk] = *(const bf16x8*)&XB[lr*136 + kk*32 + lg*8];
    f32x4 acc[4];
    #pragma unroll
    for (int ct=0;ct<4;++ct) acc[ct] = (f32x4){0.f,0.f,0.f,0.f};
    #pragma unroll
    for (int ct=0;ct<4;++ct){
        #pragma unroll
        for (int kk=0;kk<4;++kk){
            bf16x8 b0 = *(const bf16x8*)&wT[(ct*16+lr)*128 + kk*32 + lg*8];
            acc[ct] = __builtin_amdgcn_mfma_f32_16x16x32_bf16(a[kk], b0, acc[ct], 0,0,0);
        }
    }
    #pragma unroll
    for (int ct=0;ct<4;++ct){
        float bv = bu[ct*16+lr];
        #pragma unroll
        for (int i=0;i<4;++i)
            u[(size_t)(r0+lg*4+i)*64 + ct*16+lr] = fmaxf(acc[ct][i] + bv, 0.f);
    }
}

// ---------------------------------------------------------------- fused causal-update + fusion MLP
// u = relu([aggr|x]@Wu+bu); hid = relu([u|wsu]@W1+b1); fused = hid@W2+b2
__global__ __launch_bounds__(256) void k_updfus(const float* __restrict__ aggr,
                                                const float* __restrict__ x,
                                                const unsigned short* __restrict__ wuT,  // [64][128]
                                                const float* __restrict__ bu,
                                                const float* __restrict__ wsu,
                                                const unsigned short* __restrict__ w1T,  // [64][128]
                                                const float* __restrict__ b1,
                                                const unsigned short* __restrict__ w2T,  // [64][64]
                                                const float* __restrict__ b2,
                                                float* __restrict__ fused){
    __shared__ unsigned short XBs[4][16*136];
    __shared__ unsigned short X2s[4][16*136];
    int w = threadIdx.x>>6, l = threadIdx.x&63;
    int lr = l&15, lg = l>>4;
    unsigned short* XB = XBs[w];
    unsigned short* X2 = X2s[w];
    int r0 = (blockIdx.x*4 + w)*16;
    #pragma unroll
    for (int i=0;i<16;++i){
        int rr = r0+i;
        int g = rr/NF_, j = rr%NF_;
        int b = g/T_, t = g%T_, n = j/F_, f = j%F_;
        XB[i*136 + l]      = f2b(aggr[(size_t)rr*64 + l]);
        XB[i*136 + 64 + l] = f2b(x[((size_t)((b*N_+n)*F_+f)*T_ + t)*64 + l]);
        X2[i*136 + 64 + l] = f2b(wsu[((size_t)g*N_ + n)*64 + l]);
    }
    LGKM0;
    // stage 1: update GEMM k=128 -> relu -> u into X2 cols 0..63
    {
        bf16x8 a[4];
        #pragma unroll
        for (int kk=0;kk<4;++kk) a[kk] = *(const bf16x8*)&XB[lr*136 + kk*32 + lg*8];
        f32x4 acc[4];
        #pragma unroll
        for (int ct=0;ct<4;++ct) acc[ct] = (f32x4){0.f,0.f,0.f,0.f};
        #pragma unroll
        for (int ct=0;ct<4;++ct){
            #pragma unroll
            for (int kk=0;kk<4;++kk){
                bf16x8 b0 = *(const bf16x8*)&wuT[(ct*16+lr)*128 + kk*32 + lg*8];
                acc[ct] = __builtin_amdgcn_mfma_f32_16x16x32_bf16(a[kk], b0, acc[ct], 0,0,0);
            }
        }
        #pragma unroll
        for (int ct=0;ct<4;++ct){
            float bv = bu[ct*16+lr];
            #pragma unroll
            for (int i=0;i<4;++i)
                X2[(lg*4+i)*136 + ct*16+lr] = f2b(fmaxf(acc[ct][i] + bv, 0.f));
        }
    }
    LGKM0;
    // stage 2: fusion GEMM1 k=128 -> relu -> hid into XB cols 0..63
    {
        bf16x8 a[4];
        #pragma unroll
        for (int kk=0;kk<4;++kk) a[kk] = *(const bf16x8*)&X2[lr*136 + kk*32 + lg*8];
        f32x4 acc[4];
        #pragma unroll
        for (int ct=0;ct<4;++ct) acc[ct] = (f32x4){0.f,0.f,0.f,0.f};
        #pragma unroll
        for (int ct=0;ct<4;++ct){
            #pragma unroll
            for (int kk=0;kk<4;++kk){
                bf16x8 b0 = *(const bf16x8*)&w1T[(ct*16+lr)*128 + kk*32 + lg*8];
                acc[ct] = __builtin_amdgcn_mfma_f32_16x16x32_bf16(a[kk], b0, acc[ct], 0,0,0);
            }
        }
        #pragma unroll
        for (int ct=0;ct<4;++ct){
            float bv = b1[ct*16+lr];
            #pragma unroll
            for (int i=0;i<4;++i)
                XB[(lg*4+i)*136 + ct*16+lr] = f2b(fmaxf(acc[ct][i] + bv, 0.f));
        }
    }
    LGKM0;
    // stage 3: fusion GEMM2 k=64 -> fused
    {
        bf16x8 h0 = *(const bf16x8*)&XB[lr*136 + lg*8];
        bf16x8 h1 = *(const bf16x8*)&XB[lr*136 + 32 + lg*8];
        f32x4 acc[4];
        #pragma unroll
        for (int ct=0;ct<4;++ct) acc[ct] = (f32x4){0.f,0.f,0.f,0.f};
        #pragma unroll
        for (int ct=0;ct<4;++ct){
            bf16x8 b0 = *(const bf16x8*)&w2T[(ct*16+lr)*64 + lg*8];
            bf16x8 b1v= *(const bf16x8*)&w2T[(ct*16+lr)*64 + 32 + lg*8];
            acc[ct] = __builtin_amdgcn_mfma_f32_16x16x32_bf16(h0, b0, acc[ct], 0,0,0);
            acc[ct] = __builtin_amdgcn_mfma_f32_16x16x32_bf16(h1, b1v, acc[ct], 0,0,0);
        }
        #pragma unroll
        for (int ct=0;ct<4;++ct){
            float bv = b2[ct*16+lr];
            #pragma unroll
            for (int i=0;i<4;++i)
                fused[(size_t)(r0+lg*4+i)*64 + ct*16+lr] = acc[ct][i] + bv;
        }
    }
}

// ---------------------------------------------------------------- MFMA temporal transformer
#define XSTR 72    // XB stride (bf16)
#define QSTR 200   // SC stride (bf16), 12 rows
#define HSTR 136   // HID stride (bf16), 16 rows (fits in 12*200 region)

__global__ __launch_bounds__(256,4) void k_xformer(
    const float* __restrict__ fused,
    const unsigned short* __restrict__ wtq,   // [192][64] bf16  (n,k)
    const unsigned short* __restrict__ wto,   // [64][64]
    const unsigned short* __restrict__ wt1,   // [256][64]
    const unsigned short* __restrict__ wt2,   // [64][256]
    const float* __restrict__ bqkv, const float* __restrict__ bo,
    const float* __restrict__ fb1,  const float* __restrict__ fb2,
    const float* __restrict__ ln1g, const float* __restrict__ ln1b,
    const float* __restrict__ ln2g, const float* __restrict__ ln2b,
    float* __restrict__ out)
{
    __shared__ unsigned short XBs[4][16*XSTR];
    __shared__ unsigned short SCs[4][12*QSTR];

    int w  = threadIdx.x >> 6;
    int l  = threadIdx.x & 63;
    int lr = l & 15;
    int lg = l >> 4;

    unsigned short* XB  = XBs[w];
    unsigned short* SC  = SCs[w];
    unsigned short* HID = SCs[w];

    float g1[4], o1[4], g2[4], o2[4];
    #pragma unroll
    for (int nt=0;nt<4;++nt){
        g1[nt]=ln1g[nt*16+lr]; o1[nt]=ln1b[nt*16+lr];
        g2[nt]=ln2g[nt*16+lr]; o2[nt]=ln2b[nt*16+lr];
    }

    int gs = blockIdx.x*4 + w;
    int bb = gs / NF_, j = gs % NF_;
    const float* fp = fused + ((size_t)bb*T_*NF_ + j)*64;

    float res[4][4];
    #pragma unroll
    for (int nt=0;nt<4;++nt)
        #pragma unroll
        for (int i=0;i<4;++i){
            int t = lg*4+i;
            res[nt][i] = (t < 12) ? fp[(size_t)t*NF_*64 + nt*16 + lr] : 0.f;
        }

    // LN1 -> XB
    {
        float sm[4], sq[4];
        #pragma unroll
        for (int i=0;i<4;++i){
            sm[i] = res[0][i]+res[1][i]+res[2][i]+res[3][i];
            sq[i] = res[0][i]*res[0][i]+res[1][i]*res[1][i]+res[2][i]*res[2][i]+res[3][i]*res[3][i];
        }
        #pragma unroll
        for (int m=1;m<16;m<<=1){
            #pragma unroll
            for (int i=0;i<4;++i){
                sm[i] += __shfl_xor(sm[i], m, 64);
                sq[i] += __shfl_xor(sq[i], m, 64);
            }
        }
        #pragma unroll
        for (int i=0;i<4;++i){
            float mn = sm[i]*(1.0f/64.0f);
            float var = sq[i]*(1.0f/64.0f) - mn*mn;
            float rs = rsqrtf(var + 1e-5f);
            #pragma unroll
            for (int nt=0;nt<4;++nt)
                XB[(lg*4+i)*XSTR + nt*16 + lr] = f2b((res[nt][i]-mn)*rs*g1[nt] + o1[nt]);
        }
    }
    LGKM0;

    // QKV GEMM -> SC (bf16, 12 rows)
    {
        bf16x8 a0 = *(const bf16x8*)&XB[lr*XSTR + 0*32 + lg*8];
        bf16x8 a1 = *(const bf16x8*)&XB[lr*XSTR + 1*32 + lg*8];
        f32x4 acc[12];
        #pragma unroll
        for (int ct=0;ct<12;++ct) acc[ct] = (f32x4){0.f,0.f,0.f,0.f};
        #pragma unroll
        for (int ct=0;ct<12;++ct){
            bf16x8 b0 = *(const bf16x8*)&wtq[(ct*16+lr)*64 + 0*32 + lg*8];
            bf16x8 b1v= *(const bf16x8*)&wtq[(ct*16+lr)*64 + 1*32 + lg*8];
            acc[ct] = __builtin_amdgcn_mfma_f32_16x16x32_bf16(a0, b0, acc[ct], 0,0,0);
            acc[ct] = __builtin_amdgcn_mfma_f32_16x16x32_bf16(a1, b1v, acc[ct], 0,0,0);
        }
        #pragma unroll
        for (int ct=0;ct<12;++ct){
            float bv = bqkv[ct*16+lr];
            #pragma unroll
            for (int i=0;i<4;++i){
                int t = lg*4+i;
                if (t < 12) SC[t*QSTR + ct*16 + lr] = f2b(acc[ct][i] + bv);
            }
        }
    }
    LGKM0;

    // attention (48 lanes) -> O into XB
    if (l < 48){
        int hd = l/12, qt = l%12;
        float qv[16];
        {
            bf16x8 q0 = *(const bf16x8*)&SC[qt*QSTR + hd*16];
            bf16x8 q1 = *(const bf16x8*)&SC[qt*QSTR + hd*16 + 8];
            #pragma unroll
            for (int d=0;d<8;++d){ qv[d] = b2f((unsigned short)q0[d]); qv[8+d] = b2f((unsigned short)q1[d]); }
        }
        float scv[12]; float mx = -1e30f;
        #pragma unroll
        for (int kt=0;kt<12;++kt){
            bf16x8 k0 = *(const bf16x8*)&SC[kt*QSTR + 64 + hd*16];
            bf16x8 k1 = *(const bf16x8*)&SC[kt*QSTR + 64 + hd*16 + 8];
            float a = 0.f;
            #pragma unroll
            for (int d=0;d<8;++d){
                a += qv[d]  *b2f((unsigned short)k0[d]);
                a += qv[8+d]*b2f((unsigned short)k1[d]);
            }
            a *= 0.25f;
            scv[kt] = a; mx = fmaxf(mx, a);
        }
        float den = 0.f;
        #pragma unroll
        for (int kt=0;kt<12;++kt){ scv[kt] = __expf(scv[kt]-mx); den += scv[kt]; }
        float inv = 1.0f/den;
        float ov[16];
        #pragma unroll
        for (int d=0;d<16;++d) ov[d]=0.f;
        #pragma unroll
        for (int kt=0;kt<12;++kt){
            float p = scv[kt];
            bf16x8 v0 = *(const bf16x8*)&SC[kt*QSTR + 128 + hd*16];
            bf16x8 v1 = *(const bf16x8*)&SC[kt*QSTR + 128 + hd*16 + 8];
            #pragma unroll
            for (int d=0;d<8;++d){
                ov[d]   += p*b2f((unsigned short)v0[d]);
                ov[8+d] += p*b2f((unsigned short)v1[d]);
            }
        }
        bf16x8 s0, s1v;
        #pragma unroll
        for (int d=0;d<8;++d){ s0[d] = (short)f2b(ov[d]*inv); s1v[d] = (short)f2b(ov[8+d]*inv); }
        *(bf16x8*)&XB[qt*XSTR + hd*16]     = s0;
        *(bf16x8*)&XB[qt*XSTR + hd*16 + 8] = s1v;
    }
    LGKM0;

    // proj + residual -> s1
    float s1[4][4];
    {
        bf16x8 a0 = *(const bf16x8*)&XB[lr*XSTR + 0*32 + lg*8];
        bf16x8 a1 = *(const bf16x8*)&XB[lr*XSTR + 1*32 + lg*8];
        f32x4 pacc[4];
        #pragma unroll
        for (int ct=0;ct<4;++ct) pacc[ct] = (f32x4){0.f,0.f,0.f,0.f};
        #pragma unroll
        for (int ct=0;ct<4;++ct){
            bf16x8 b0 = *(const bf16x8*)&wto[(ct*16+lr)*64 + 0*32 + lg*8];
            bf16x8 b1v= *(const bf16x8*)&wto[(ct*16+lr)*64 + 1*32 + lg*8];
            pacc[ct] = __builtin_amdgcn_mfma_f32_16x16x32_bf16(a0, b0, pacc[ct], 0,0,0);
            pacc[ct] = __builtin_amdgcn_mfma_f32_16x16x32_bf16(a1, b1v, pacc[ct], 0,0,0);
        }
        #pragma unroll
        for (int ct=0;ct<4;++ct){
            float bv = bo[ct*16+lr];
            #pragma unroll
            for (int i=0;i<4;++i)
                s1[ct][i] = res[ct][i] + pacc[ct][i] + bv;
        }
    }

    // LN2 -> XB
    {
        float sm[4], sq[4];
        #pragma unroll
        for (int i=0;i<4;++i){
            sm[i] = s1[0][i]+s1[1][i]+s1[2][i]+s1[3][i];
            sq[i] = s1[0][i]*s1[0][i]+s1[1][i]*s1[1][i]+s1[2][i]*s1[2][i]+s1[3][i]*s1[3][i];
        }
        #pragma unroll
        for (int m=1;m<16;m<<=1){
            #pragma unroll
            for (int i=0;i<4;++i){
                sm[i] += __shfl_xor(sm[i], m, 64);
                sq[i] += __shfl_xor(sq[i], m, 64);
            }
        }
        #pragma unroll
        for (int i=0;i<4;++i){
            float mn = sm[i]*(1.0f/64.0f);
            float var = sq[i]*(1.0f/64.0f) - mn*mn;
            float rs = rsqrtf(var + 1e-5f);
            #pragma unroll
            for (int nt=0;nt<4;++nt)
                XB[(lg*4+i)*XSTR + nt*16 + lr] = f2b((s1[nt][i]-mn)*rs*g2[nt] + o2[nt]);
        }
    }
    LGKM0;

    // FFN in two 128-wide halves
    f32x4 oacc[4];
    #pragma unroll
    for (int ct=0;ct<4;++ct) oacc[ct] = (f32x4){0.f,0.f,0.f,0.f};
    {
        bf16x8 a0 = *(const bf16x8*)&XB[lr*XSTR + 0*32 + lg*8];
        bf16x8 a1 = *(const bf16x8*)&XB[lr*XSTR + 1*32 + lg*8];
        #pragma unroll
        for (int half=0; half<2; ++half){
            LGKM0;
            f32x4 facc[8];
            #pragma unroll
            for (int c=0;c<8;++c) facc[c] = (f32x4){0.f,0.f,0.f,0.f};
            #pragma unroll
            for (int c=0;c<8;++c){
                int ct = half*8 + c;
                bf16x8 b0 = *(const bf16x8*)&wt1[(ct*16+lr)*64 + 0*32 + lg*8];
                bf16x8 b1v= *(const bf16x8*)&wt1[(ct*16+lr)*64 + 1*32 + lg*8];
                facc[c] = __builtin_amdgcn_mfma_f32_16x16x32_bf16(a0, b0, facc[c], 0,0,0);
                facc[c] = __builtin_amdgcn_mfma_f32_16x16x32_bf16(a1, b1v, facc[c], 0,0,0);
            }
            #pragma unroll
            for (int c=0;c<8;++c){
                int ct = half*8 + c;
                float bv = fb1[ct*16+lr];
                #pragma unroll
                for (int i=0;i<4;++i){
                    float xv = facc[c][i] + bv;
                    float u = 0.7978845608f*(xv + 0.044715f*xv*xv*xv);
                    float e = __expf(-2.0f*fabsf(u));
                    float th = (1.0f-e)/(1.0f+e);
                    th = (u < 0.f) ? -th : th;
                    HID[(lg*4+i)*HSTR + c*16 + lr] = f2b(0.5f*xv*(1.0f+th));
                }
            }
            LGKM0;
            #pragma unroll
            for (int ks=0;ks<4;++ks){
                bf16x8 af = *(const bf16x8*)&HID[lr*HSTR + ks*32 + lg*8];
                #pragma unroll
                for (int ct=0;ct<4;++ct){
                    bf16x8 bfr = *(const bf16x8*)&wt2[(ct*16+lr)*256 + half*128 + ks*32 + lg*8];
                    oacc[ct] = __builtin_amdgcn_mfma_f32_16x16x32_bf16(af, bfr, oacc[ct], 0,0,0);
                }
            }
        }
    }

    // residual + mean over t
    #pragma unroll
    for (int ct=0;ct<4;++ct){
        float bv = fb2[ct*16+lr];
        float part = 0.f;
        #pragma unroll
        for (int i=0;i<4;++i){
            if (lg*4+i < 12) part += s1[ct][i] + oacc[ct][i] + bv;
        }
        part += __shfl_xor(part, 16, 64);
        part += __shfl_xor(part, 32, 64);
        if (lg == 0) out[(size_t)gs*64 + ct*16 + lr] = part*(1.0f/12.0f);
    }
}

// ----------------------------------------------------------------
extern "C" void kernel_launch(void* const* d_in, const int* in_sizes, int n_in,
                              void* d_out, int out_size, void* d_ws, size_t ws_size,
                              hipStream_t stream) {
    const float* x      = (const float*)d_in[0];
    const int*   r_ei   = (const int*)  d_in[1];
    const float* r_ea   = (const float*)d_in[2];
    const int*   c_ei   = (const int*)  d_in[3];
    const float* c_ew   = (const float*)d_in[4];
    const float* rvWlin = (const float*)d_in[5];
    const float* rvblin = (const float*)d_in[6];
    const float* rvWupd = (const float*)d_in[7];
    const float* rvbupd = (const float*)d_in[8];
    const float* rvgate = (const float*)d_in[9];
    const float* rvlw   = (const float*)d_in[10];
    const float* csWlin = (const float*)d_in[11];
    const float* csblin = (const float*)d_in[12];
    const float* csWupd = (const float*)d_in[13];
    const float* csbupd = (const float*)d_in[14];
    const float* csgate = (const float*)d_in[15];
    const float* cslw   = (const float*)d_in[16];
    const float* fuW1   = (const float*)d_in[17];
    const float* fub1   = (const float*)d_in[18];
    const float* fuW2   = (const float*)d_in[19];
    const float* fub2   = (const float*)d_in[20];
    const float* ln1g   = (const float*)d_in[21];
    const float* ln1b   = (const float*)d_in[22];
    const float* ln2g   = (const float*)d_in[23];
    const float* ln2b   = (const float*)d_in[24];
    const float* Wqkv   = (const float*)d_in[25];
    const float* bqkv   = (const float*)d_in[26];
    const float* Wo     = (const float*)d_in[27];
    const float* bo     = (const float*)d_in[28];
    const float* ffW1   = (const float*)d_in[29];
    const float* ffb1   = (const float*)d_in[30];
    const float* ffW2   = (const float*)d_in[31];
    const float* ffb2   = (const float*)d_in[32];

    float* wsp  = (float*)d_ws;
    float* FNY  = wsp;                               // 12,288,000: causal y, then FUSED
    float* FNA  = wsp + 12288000;                    // 12,288,000: causal aggr
    float* WS   = wsp + 24576000;                    //  1,536,000
    float* WSY  = wsp + 26112000;                    //  1,536,000: river y
    float* WSA  = wsp + 27648000;                    //  1,536,000: river aggr
    float* WSU  = wsp + 29184000;                    //  1,536,000: CSR scratch, then river update out
    unsigned short* wt = (unsigned short*)(wsp + 30720000);   // 86,016 bf16
    float* outp = (float*)d_out;

    // CSR layout inside WSU region (dead until k_upd16 writes it)
    int* ibase  = (int*)WSU;
    int* cnt_c  = ibase;           // 8000
    int* cnt_r  = ibase + 8000;    // 1000
    int* off_c  = ibase + 9000;    // 8001
    int* off_r  = ibase + 17001;   // 1001
    int* cur_c  = ibase + 18002;   // 8000
    int* cur_r  = ibase + 26002;   // 1000
    int* eidx_c = ibase + 27002;   // 24000
    int* eidx_r = ibase + 51002;   // 2000
    float* mw_c = (float*)(ibase + 53002); // 24000
    float* mw_r = (float*)(ibase + 77002); // 2000

    const int* c_src = c_ei;
    const int* c_dst = c_ei + EC_;
    const int* r_src = r_ei;
    const int* r_dst = r_ei + ER_;

    hipMemsetAsync(cnt_c, 0, 9000*sizeof(int), stream);

    // weight panels + CSR build
    k_prepw<<<336, 256, 0, stream>>>(Wqkv, Wo, ffW1, ffW2, csWlin, rvWlin, csWupd, rvWupd,
                                     fuW1, fuW2, wt);
    k_mwhist<<<(EC_+ER_+255)/256, 256, 0, stream>>>(c_dst, r_dst, c_ew, cslw, csgate,
                                                    r_ea, rvlw, rvgate, mw_c, mw_r, cnt_c, cnt_r);
    k_scan<<<2, 256, 0, stream>>>(cnt_c, off_c, cur_c, cnt_r, off_r, cur_r);
    k_fill<<<(EC_+ER_+255)/256, 256, 0, stream>>>(c_dst, r_dst, cur_c, cur_r, eidx_c, eidx_r);

    // watershed repr + node linear transforms
    k_ws<<<G_*N_, 64, 0, stream>>>(x, WS);
    k_lin16<false><<<(G_*N_)/64, 256, 0, stream>>>(WS, nullptr, wt+53248, rvblin, WSY);
    k_lin16<true ><<<(G_*NF_)/64, 256, 0, stream>>>(nullptr, x, wt+49152, csblin, FNY);

    // gather-aggregation (no atomics, writes every row)
    k_gaggr<<<(G_*N_)/4, 256, 0, stream>>>(WSY, r_src, eidx_r, off_r, mw_r, WSA, N_, (G_*N_)/4/8);
    k_gaggr<<<(G_*NF_)/4, 256, 0, stream>>>(FNY, c_src, eidx_c, off_c, mw_c, FNA, NF_, (G_*NF_)/4/8);

    // river update (clobbers CSR scratch -> OK, consumers done)
    k_upd16<<<(G_*N_)/64, 256, 0, stream>>>(WSA, WS, wt+65536, rvbupd, WSU);

    // fused causal update + fusion MLP -> FUSED (into FNY region)
    k_updfus<<<(G_*NF_)/64, 256, 0, stream>>>(FNA, x, wt+57344, csbupd, WSU,
                                              wt+73728, fub1, wt+81920, fub2, FNY);

    // MFMA temporal transformer + time-mean -> out
    k_xformer<<<(B_*N_*F_)/4, 256, 0, stream>>>(FNY,
                                                wt, wt+12288, wt+16384, wt+32768,
                                                bqkv, bo, ffb1, ffb2,
                                                ln1g, ln1b, ln2g, ln2b,
                                                outp);
}